// Round 5
// baseline (1562.544 us; speedup 1.0000x reference)
//
#include <hip/hip_runtime.h>
#include <hip/hip_bf16.h>

typedef __hip_bfloat16 bf16;

#define IN_C 128

// ---- dtype detection: flag=1 if buffer is bf16, 0 if float32 ----
__global__ __launch_bounds__(256) void detect_k(const unsigned short* __restrict__ xb,
                                                int* __restrict__ flag) {
  __shared__ int s_sane;
  if (threadIdx.x == 0) s_sane = 0;
  __syncthreads();
  int sane = 0;
  for (int i = threadIdx.x; i < 4096; i += 256) {
    unsigned short h = xb[2 * i];
    int e = (h >> 7) & 0xFF;
    if (e >= 100 && e <= 150) sane++;
  }
  atomicAdd(&s_sane, sane);
  __syncthreads();
  if (threadIdx.x == 0) *flag = (s_sane > 3072) ? 1 : 0;
}

__global__ __launch_bounds__(256) void cvt_k(const void* __restrict__ in,
                                             float* __restrict__ out, int n,
                                             const int* __restrict__ flag) {
  int i = blockIdx.x * 256 + threadIdx.x;
  if (i >= n) return;
  if (*flag) out[i] = __bfloat162float(((const bf16*)in)[i]);
  else       out[i] = ((const float*)in)[i];
}

struct WArgs { const void* p[14]; int off[15]; };
__global__ __launch_bounds__(256) void cvtw_k(WArgs a, float* __restrict__ out,
                                              const int* __restrict__ flag, int total) {
  int i = blockIdx.x * 256 + threadIdx.x;
  if (i >= total) return;
  int s = 0;
#pragma unroll
  for (int j = 1; j < 14; j++) if (i >= a.off[j]) s = j;
  int loc = i - a.off[s];
  if (*flag) out[i] = __bfloat162float(((const bf16*)a.p[s])[loc]);
  else       out[i] = ((const float*)a.p[s])[loc];
}

__global__ __launch_bounds__(256) void out_k(const float* __restrict__ src,
                                             void* __restrict__ out, int n,
                                             const int* __restrict__ flag) {
  int i = blockIdx.x * 256 + threadIdx.x;
  if (i >= n) return;
  float v = src[i];
  if (*flag) ((bf16*)out)[i] = __float2bfloat16(v);
  else       ((float*)out)[i] = v;
}

// out[n,C] = act((x[n,K]+preb) @ W[K,C] + postb)
// ACT: 0 none, 1 leaky(0.01), 2 relu.
// NRM: 0 none; 1 out=normalized rows; 3 out=raw rows, out2[row]=1/max(||row||,eps) (C==64 only)
template <int K, int C, int ACT, bool PREB, bool POSTB, int NRM>
__global__ __launch_bounds__(256) void lin_k(const float* __restrict__ x,
                                             const float* __restrict__ W,
                                             const float* __restrict__ preb,
                                             const float* __restrict__ postb,
                                             float* __restrict__ out,
                                             float* __restrict__ out2, int n) {
  constexpr int G = 256 / C;
  constexpr int R = 8;
  constexpr int RPB = G * R;
  __shared__ float xs[RPB * K];
  const int tid = threadIdx.x;
  const int row0 = blockIdx.x * RPB;
  for (int i = tid; i < RPB * K; i += 256) {
    int r = i / K, k = i - r * K;
    int row = row0 + r;
    float v = 0.f;
    if (row < n) v = x[(size_t)row * K + k];
    if (PREB) v += preb[k];
    xs[i] = v;
  }
  __syncthreads();
  const int c = tid % C;
  const int g = tid / C;
  float acc[R];
#pragma unroll
  for (int r = 0; r < R; r++) acc[r] = 0.f;
  const float* xg = xs + g * R * K;
  for (int k = 0; k < K; k += 4) {
    float w0 = W[(k + 0) * C + c];
    float w1 = W[(k + 1) * C + c];
    float w2 = W[(k + 2) * C + c];
    float w3 = W[(k + 3) * C + c];
#pragma unroll
    for (int r = 0; r < R; r++) {
      const float* xp = xg + r * K + k;
      acc[r] += xp[0] * w0;
      acc[r] += xp[1] * w1;
      acc[r] += xp[2] * w2;
      acc[r] += xp[3] * w3;
    }
  }
  float pb = POSTB ? postb[c] : 0.f;
#pragma unroll
  for (int r = 0; r < R; r++) {
    float v = acc[r] + pb;
    if (ACT == 1) v = (v >= 0.f) ? v : 0.01f * v;
    if (ACT == 2) v = (v > 0.f) ? v : 0.f;
    int row = row0 + g * R + r;
    if (NRM == 0) {
      if (row < n) out[(size_t)row * C + c] = v;
    } else {
      // C==64: one wave holds the full row -> shfl reduce sumsq
      float ss = v * v;
#pragma unroll
      for (int o = 32; o > 0; o >>= 1) ss += __shfl_xor(ss, o);
      float inv = 1.0f / fmaxf(sqrtf(ss), 1e-12f);
      if (row < n) {
        if (NRM == 1) {
          out[(size_t)row * C + c] = v * inv;
        } else {  // NRM == 3
          out[(size_t)row * C + c] = v;
          if (c == 0) out2[row] = inv;
        }
      }
    }
  }
}

// ---- CSR build ----
__global__ __launch_bounds__(256) void count_k(const int* __restrict__ src,
                                               const int* __restrict__ dst,
                                               int* __restrict__ cnt_s,
                                               int* __restrict__ cnt_d, int E) {
  int e = blockIdx.x * 256 + threadIdx.x;
  if (e >= E) return;
  atomicAdd(&cnt_s[src[e]], 1);
  atomicAdd(&cnt_d[dst[e]], 1);
}

// hierarchical exclusive scan, 2048 elems/block, gridDim.y selects {src,dst}
__global__ __launch_bounds__(256) void scan_local_k(const int* __restrict__ cnt_s,
                                                    const int* __restrict__ cnt_d,
                                                    int* __restrict__ off_s,
                                                    int* __restrict__ off_d,
                                                    int* __restrict__ part, int nb, int n) {
  const int* cnt = blockIdx.y ? cnt_d : cnt_s;
  int* off = blockIdx.y ? off_d : off_s;
  __shared__ int sd[256];
  int t = threadIdx.x;
  int base = blockIdx.x * 2048 + t * 8;
  int v[8], s = 0;
#pragma unroll
  for (int j = 0; j < 8; j++) {
    int idx = base + j;
    v[j] = (idx < n) ? cnt[idx] : 0;
    s += v[j];
  }
  sd[t] = s;
  __syncthreads();
  for (int o = 1; o < 256; o <<= 1) {
    int x = (t >= o) ? sd[t - o] : 0;
    __syncthreads();
    sd[t] += x;
    __syncthreads();
  }
  int excl = sd[t] - s;
  if (t == 255) part[blockIdx.y * nb + blockIdx.x] = sd[255];
  int run = excl;
#pragma unroll
  for (int j = 0; j < 8; j++) {
    int idx = base + j;
    if (idx < n) off[idx] = run;
    run += v[j];
  }
}

__global__ __launch_bounds__(256) void scan_add_k(int* __restrict__ off_s,
                                                  int* __restrict__ off_d,
                                                  int* __restrict__ cur_s,
                                                  int* __restrict__ cur_d,
                                                  const int* __restrict__ part,
                                                  int nb, int n) {
  int* off = blockIdx.y ? off_d : off_s;
  int* cur = blockIdx.y ? cur_d : cur_s;
  const int* p = part + blockIdx.y * nb;
  __shared__ int s_pref;
  if (threadIdx.x == 0) {
    int s = 0;
    for (int i = 0; i < (int)blockIdx.x; i++) s += p[i];
    s_pref = s;
    if (blockIdx.x == 0) {
      int tot = 0;
      for (int i = 0; i < nb; i++) tot += p[i];
      off[n] = tot;
    }
  }
  __syncthreads();
  int pref = s_pref;
  int base = blockIdx.x * 2048 + threadIdx.x * 8;
#pragma unroll
  for (int j = 0; j < 8; j++) {
    int idx = base + j;
    if (idx < n) { int val = off[idx] + pref; off[idx] = val; cur[idx] = val; }
  }
}

// fill: only 2 scatters now (sl_d for src-CSR, dl_src for dst-CSR)
__global__ __launch_bounds__(256) void fill_k(const int* __restrict__ src,
                                              const int* __restrict__ dst,
                                              int* __restrict__ cur_s, int* __restrict__ cur_d,
                                              int* __restrict__ sl_d,
                                              int* __restrict__ dl_src, int E) {
  int e = blockIdx.x * 256 + threadIdx.x;
  if (e >= E) return;
  int s = src[e], d = dst[e];
  int ps = atomicAdd(&cur_s[s], 1);
  int pd = atomicAdd(&cur_d[d], 1);
  sl_d[ps] = d;
  dl_src[pd] = s;
}

// ---- Phase S: per src node, compute den = sum exp(v); PK[s]={inv_norm, 1/den} ----
__global__ __launch_bounds__(256) void den_k(const float* __restrict__ XL,
                                             const float* __restrict__ SLI,
                                             const float* __restrict__ XRN,
                                             const int* __restrict__ off_s,
                                             const int* __restrict__ sl_d,
                                             float2* __restrict__ PK, int n) {
  int wv = threadIdx.x >> 6, lane = threadIdx.x & 63;
  int node = blockIdx.x * 4 + wv;
  if (node >= n) return;
  int q = lane >> 4, ql = lane & 15;
  int beg = off_s[node];
  int deg = off_s[node + 1] - beg;
  float sli = SLI[node];
  float4 xl = *(const float4*)&XL[(size_t)node * 64 + ql * 4];
  float den = 0.f;
  for (int i0 = 0; i0 < deg; i0 += 4) {
    int i = i0 + q;
    if (i < deg) {
      int d = sl_d[beg + i];
      float4 xr = *(const float4*)&XRN[(size_t)d * 64 + ql * 4];
      float p = xl.x * xr.x + xl.y * xr.y + xl.z * xr.z + xl.w * xr.w;
      p += __shfl_xor(p, 1, 16); p += __shfl_xor(p, 2, 16);
      p += __shfl_xor(p, 4, 16); p += __shfl_xor(p, 8, 16);
      if (ql == 0) den += __expf(__expf(p * sli) * 4.0f);  // v=exp(cos)/TAU
    }
  }
  den += __shfl_xor(den, 16);
  den += __shfl_xor(den, 32);
  if (lane == 0) PK[node] = make_float2(sli, 1.0f / den);
}

// ---- Phase D: per dst node, recompute a and aggregate; one write per node ----
__global__ __launch_bounds__(256) void gat_dst_k(const float* __restrict__ XL,
                                                 const float* __restrict__ XRN,
                                                 const float2* __restrict__ PK,
                                                 const int* __restrict__ off_d,
                                                 const int* __restrict__ dl_src,
                                                 float* __restrict__ AGG, int n) {
  int wv = threadIdx.x >> 6, lane = threadIdx.x & 63;
  int node = blockIdx.x * 4 + wv;
  if (node >= n) return;
  int q = lane >> 4, ql = lane & 15;
  int beg = off_d[node];
  int deg = off_d[node + 1] - beg;
  float4 xr = *(const float4*)&XRN[(size_t)node * 64 + ql * 4];
  float4 acc = {0.f, 0.f, 0.f, 0.f};
  for (int i0 = 0; i0 < deg; i0 += 4) {
    int i = i0 + q;
    if (i < deg) {
      int s = dl_src[beg + i];
      float4 xv = *(const float4*)&XL[(size_t)s * 64 + ql * 4];
      float p = xv.x * xr.x + xv.y * xr.y + xv.z * xr.z + xv.w * xr.w;
      p += __shfl_xor(p, 1, 16); p += __shfl_xor(p, 2, 16);
      p += __shfl_xor(p, 4, 16); p += __shfl_xor(p, 8, 16);
      float w = 0.f;
      if (ql == 0) {
        float2 pk = PK[s];
        w = __expf(__expf(p * pk.x) * 4.0f) * pk.y;  // a = exp(v)/den
      }
      w = __shfl(w, 0, 16);
      acc.x += w * xv.x; acc.y += w * xv.y; acc.z += w * xv.z; acc.w += w * xv.w;
    }
  }
  acc.x += __shfl_xor(acc.x, 16); acc.y += __shfl_xor(acc.y, 16);
  acc.z += __shfl_xor(acc.z, 16); acc.w += __shfl_xor(acc.w, 16);
  acc.x += __shfl_xor(acc.x, 32); acc.y += __shfl_xor(acc.y, 32);
  acc.z += __shfl_xor(acc.z, 32); acc.w += __shfl_xor(acc.w, 32);
  if (q == 0) *(float4*)&AGG[(size_t)node * 64 + ql * 4] = acc;
}

extern "C" void kernel_launch(void* const* d_in, const int* in_sizes, int n_in,
                              void* d_out, int out_size, void* d_ws, size_t ws_size,
                              hipStream_t stream) {
  const int N = in_sizes[0] / IN_C;
  const int E = in_sizes[1] / 2;
  const int* ei  = (const int*)d_in[1];
  const int* src = ei;
  const int* dst = ei + E;

  // ---- workspace layout (8B-aligned chunks) ----
  char* wsb = (char*)d_ws;
  size_t o = 0;
  auto alloc = [&](size_t elems) { void* p = wsb + o; o += ((elems + 1) & ~1ull) * 4; return p; };
  int*    FLAG   = (int*)alloc(16);
  float*  WF     = (float*)alloc(60000);
  int*    CNT_S  = (int*)alloc(N);
  int*    CNT_D  = (int*)alloc(N);
  int*    OFF_S  = (int*)alloc(N + 1);
  int*    OFF_D  = (int*)alloc(N + 1);
  int*    CUR_S  = (int*)alloc(N);
  int*    CUR_D  = (int*)alloc(N);
  int*    PART   = (int*)alloc(256);
  int*    SL_D   = (int*)alloc(E);
  int*    DL_SRC = (int*)alloc(E);
  float*  SLI    = (float*)alloc(N);
  float2* PK     = (float2*)alloc((size_t)N * 2);
  float*  bufA   = (float*)alloc((size_t)N * 128);  // XF -> XRN(upper) / OUTF(lower)
  float*  bufB   = (float*)alloc((size_t)N * 128);  // H0 -> AGG1/Hb/T | AGG2/H2
  float*  bufC   = (float*)alloc((size_t)N * 64);   // XL raw

  float* XF  = bufA;
  float* XRN = bufA + (size_t)N * 64;
  float* H0  = bufB;
  float* B1  = bufB;                    // AGG1 / Hb / T
  float* B2  = bufB + (size_t)N * 64;   // AGG2 / H2
  float* XL  = bufC;

  dim3 blk(256);
  auto nblk = [](long total, int per) { return dim3((unsigned)((total + per - 1) / per)); };

  // ---- dtype detect + convert ----
  detect_k<<<1, blk, 0, stream>>>((const unsigned short*)d_in[0], FLAG);
  cvt_k<<<nblk((long)N * 128, 256), blk, 0, stream>>>(d_in[0], XF, N * 128, FLAG);
  WArgs wa;
  int wtot = 0;
  float* wp[16];
  for (int i = 2; i < 16; i++) {
    wa.p[i - 2] = d_in[i];
    wa.off[i - 2] = wtot;
    wp[i] = WF + wtot;
    wtot += in_sizes[i];
  }
  wa.off[14] = wtot;
  cvtw_k<<<nblk(wtot, 256), blk, 0, stream>>>(wa, WF, FLAG, wtot);
  const float *W_in = wp[2], *b_in = wp[3], *Wl1 = wp[4], *Wr1 = wp[5],
              *bias1 = wp[6], *Wc1 = wp[7], *Wl2 = wp[8], *Wr2 = wp[9],
              *bias2 = wp[10], *Wc2 = wp[11], *W3 = wp[12], *b3 = wp[13],
              *W4 = wp[14], *b4 = wp[15];

  // ---- CSR build (once; both GAT layers share the graph) ----
  hipMemsetAsync(CNT_S, 0, sizeof(int) * (size_t)N * 2, stream);  // CNT_S, CNT_D contiguous
  count_k<<<nblk(E, 256), blk, 0, stream>>>(src, dst, CNT_S, CNT_D, E);
  {
    int nb = (N + 2047) / 2048;
    dim3 g(nb, 2);
    scan_local_k<<<g, blk, 0, stream>>>(CNT_S, CNT_D, OFF_S, OFF_D, PART, nb, N);
    scan_add_k<<<g, blk, 0, stream>>>(OFF_S, OFF_D, CUR_S, CUR_D, PART, nb, N);
  }
  fill_k<<<nblk(E, 256), blk, 0, stream>>>(src, dst, CUR_S, CUR_D, SL_D, DL_SRC, E);

  // h0 = leaky(x @ W_in + b_in)
  lin_k<128, 128, 1, false, true, 0>
      <<<nblk(N, 16), blk, 0, stream>>>(XF, W_in, nullptr, b_in, H0, nullptr, N);

  // ---- GAT layer 1 ----
  lin_k<128, 64, 0, false, false, 3>   // XL raw -> bufC, SLI
      <<<nblk(N, 32), blk, 0, stream>>>(H0, Wl1, nullptr, nullptr, XL, SLI, N);
  lin_k<128, 64, 0, false, false, 1>   // XRN normalized
      <<<nblk(N, 32), blk, 0, stream>>>(H0, Wr1, nullptr, nullptr, XRN, nullptr, N);
  den_k<<<nblk(N, 4), blk, 0, stream>>>(XL, SLI, XRN, OFF_S, SL_D, PK, N);
  gat_dst_k<<<nblk(N, 4), blk, 0, stream>>>(XL, XRN, PK, OFF_D, DL_SRC, B1, N);
  lin_k<64, 64, 1, true, false, 0>
      <<<nblk(N, 32), blk, 0, stream>>>(B1, Wc1, bias1, nullptr, B1, nullptr, N);

  // ---- GAT layer 2 ----
  lin_k<64, 64, 0, false, false, 3>
      <<<nblk(N, 32), blk, 0, stream>>>(B1, Wl2, nullptr, nullptr, XL, SLI, N);
  lin_k<64, 64, 0, false, false, 1>
      <<<nblk(N, 32), blk, 0, stream>>>(B1, Wr2, nullptr, nullptr, XRN, nullptr, N);
  den_k<<<nblk(N, 4), blk, 0, stream>>>(XL, SLI, XRN, OFF_S, SL_D, PK, N);
  gat_dst_k<<<nblk(N, 4), blk, 0, stream>>>(XL, XRN, PK, OFF_D, DL_SRC, B2, N);
  lin_k<64, 64, 1, true, false, 0>
      <<<nblk(N, 32), blk, 0, stream>>>(B2, Wc2, bias2, nullptr, B2, nullptr, N);

  // ---- head ----
  lin_k<64, 64, 2, false, true, 0>
      <<<nblk(N, 32), blk, 0, stream>>>(B2, W3, nullptr, b3, B1, nullptr, N);
  lin_k<64, 32, 0, false, true, 0>
      <<<nblk(N, 64), blk, 0, stream>>>(B1, W4, nullptr, b4, bufA, nullptr, N);
  out_k<<<nblk((long)N * 32, 256), blk, 0, stream>>>(bufA, d_out, N * 32, FLAG);
}

// Round 6
// 1389.509 us; speedup vs baseline: 1.1245x; 1.1245x over previous
//
#include <hip/hip_runtime.h>
#include <hip/hip_bf16.h>

typedef __hip_bfloat16 bf16;

#define IN_C 128

// ---- dtype detection: flag=1 if buffer is bf16, 0 if float32 ----
__global__ __launch_bounds__(256) void detect_k(const unsigned short* __restrict__ xb,
                                                int* __restrict__ flag) {
  __shared__ int s_sane;
  if (threadIdx.x == 0) s_sane = 0;
  __syncthreads();
  int sane = 0;
  for (int i = threadIdx.x; i < 4096; i += 256) {
    unsigned short h = xb[2 * i];
    int e = (h >> 7) & 0xFF;
    if (e >= 100 && e <= 150) sane++;
  }
  atomicAdd(&s_sane, sane);
  __syncthreads();
  if (threadIdx.x == 0) *flag = (s_sane > 3072) ? 1 : 0;
}

__global__ __launch_bounds__(256) void cvt_k(const void* __restrict__ in,
                                             float* __restrict__ out, int n,
                                             const int* __restrict__ flag) {
  int i = blockIdx.x * 256 + threadIdx.x;
  if (i >= n) return;
  if (*flag) out[i] = __bfloat162float(((const bf16*)in)[i]);
  else       out[i] = ((const float*)in)[i];
}

struct WArgs { const void* p[14]; int off[15]; };
__global__ __launch_bounds__(256) void cvtw_k(WArgs a, float* __restrict__ out,
                                              const int* __restrict__ flag, int total) {
  int i = blockIdx.x * 256 + threadIdx.x;
  if (i >= total) return;
  int s = 0;
#pragma unroll
  for (int j = 1; j < 14; j++) if (i >= a.off[j]) s = j;
  int loc = i - a.off[s];
  if (*flag) out[i] = __bfloat162float(((const bf16*)a.p[s])[loc]);
  else       out[i] = ((const float*)a.p[s])[loc];
}

__global__ __launch_bounds__(256) void out_k(const float* __restrict__ src,
                                             void* __restrict__ out, int n,
                                             const int* __restrict__ flag) {
  int i = blockIdx.x * 256 + threadIdx.x;
  if (i >= n) return;
  float v = src[i];
  if (*flag) ((bf16*)out)[i] = __float2bfloat16(v);
  else       ((float*)out)[i] = v;
}

// out[n,C] = act((x[n,K]+preb) @ W[K,C] + postb)
// ACT: 0 none, 1 leaky(0.01), 2 relu.
// NRM: 0 none; 1 out=normalized rows; 3 out=raw rows, out2[row]=1/max(||row||,eps) (C==64 only)
template <int K, int C, int ACT, bool PREB, bool POSTB, int NRM>
__global__ __launch_bounds__(256) void lin_k(const float* __restrict__ x,
                                             const float* __restrict__ W,
                                             const float* __restrict__ preb,
                                             const float* __restrict__ postb,
                                             float* __restrict__ out,
                                             float* __restrict__ out2, int n) {
  constexpr int G = 256 / C;
  constexpr int R = 8;
  constexpr int RPB = G * R;
  __shared__ float xs[RPB * K];
  const int tid = threadIdx.x;
  const int row0 = blockIdx.x * RPB;
  for (int i = tid; i < RPB * K; i += 256) {
    int r = i / K, k = i - r * K;
    int row = row0 + r;
    float v = 0.f;
    if (row < n) v = x[(size_t)row * K + k];
    if (PREB) v += preb[k];
    xs[i] = v;
  }
  __syncthreads();
  const int c = tid % C;
  const int g = tid / C;
  float acc[R];
#pragma unroll
  for (int r = 0; r < R; r++) acc[r] = 0.f;
  const float* xg = xs + g * R * K;
  for (int k = 0; k < K; k += 4) {
    float w0 = W[(k + 0) * C + c];
    float w1 = W[(k + 1) * C + c];
    float w2 = W[(k + 2) * C + c];
    float w3 = W[(k + 3) * C + c];
#pragma unroll
    for (int r = 0; r < R; r++) {
      const float* xp = xg + r * K + k;
      acc[r] += xp[0] * w0;
      acc[r] += xp[1] * w1;
      acc[r] += xp[2] * w2;
      acc[r] += xp[3] * w3;
    }
  }
  float pb = POSTB ? postb[c] : 0.f;
#pragma unroll
  for (int r = 0; r < R; r++) {
    float v = acc[r] + pb;
    if (ACT == 1) v = (v >= 0.f) ? v : 0.01f * v;
    if (ACT == 2) v = (v > 0.f) ? v : 0.f;
    int row = row0 + g * R + r;
    if (NRM == 0) {
      if (row < n) out[(size_t)row * C + c] = v;
    } else {
      // C==64: one wave holds the full row -> shfl reduce sumsq
      float ss = v * v;
#pragma unroll
      for (int o = 32; o > 0; o >>= 1) ss += __shfl_xor(ss, o);
      float inv = 1.0f / fmaxf(sqrtf(ss), 1e-12f);
      if (row < n) {
        if (NRM == 1) {
          out[(size_t)row * C + c] = v * inv;
        } else {  // NRM == 3
          out[(size_t)row * C + c] = v;
          if (c == 0) out2[row] = inv;
        }
      }
    }
  }
}

// ---- CSR build (dst side only) ----
__global__ __launch_bounds__(256) void count_k(const int* __restrict__ dst,
                                               int* __restrict__ cnt_d, int E) {
  int e = blockIdx.x * 256 + threadIdx.x;
  if (e >= E) return;
  atomicAdd(&cnt_d[dst[e]], 1);
}

// hierarchical exclusive scan, 2048 elems/block
__global__ __launch_bounds__(256) void scan_local_k(const int* __restrict__ cnt,
                                                    int* __restrict__ off,
                                                    int* __restrict__ part, int n) {
  __shared__ int sd[256];
  int t = threadIdx.x;
  int base = blockIdx.x * 2048 + t * 8;
  int v[8], s = 0;
#pragma unroll
  for (int j = 0; j < 8; j++) {
    int idx = base + j;
    v[j] = (idx < n) ? cnt[idx] : 0;
    s += v[j];
  }
  sd[t] = s;
  __syncthreads();
  for (int o = 1; o < 256; o <<= 1) {
    int x = (t >= o) ? sd[t - o] : 0;
    __syncthreads();
    sd[t] += x;
    __syncthreads();
  }
  int excl = sd[t] - s;
  if (t == 255) part[blockIdx.x] = sd[255];
  int run = excl;
#pragma unroll
  for (int j = 0; j < 8; j++) {
    int idx = base + j;
    if (idx < n) off[idx] = run;
    run += v[j];
  }
}

__global__ __launch_bounds__(256) void scan_add_k(int* __restrict__ off,
                                                  int* __restrict__ cur,
                                                  const int* __restrict__ part,
                                                  int nb, int n) {
  __shared__ int s_pref;
  if (threadIdx.x == 0) {
    int s = 0;
    for (int i = 0; i < (int)blockIdx.x; i++) s += part[i];
    s_pref = s;
    if (blockIdx.x == 0) {
      int tot = 0;
      for (int i = 0; i < nb; i++) tot += part[i];
      off[n] = tot;
    }
  }
  __syncthreads();
  int pref = s_pref;
  int base = blockIdx.x * 2048 + threadIdx.x * 8;
#pragma unroll
  for (int j = 0; j < 8; j++) {
    int idx = base + j;
    if (idx < n) { int val = off[idx] + pref; off[idx] = val; cur[idx] = val; }
  }
}

// fill: single scatter (dst-CSR only)
__global__ __launch_bounds__(256) void fill_k(const int* __restrict__ src,
                                              const int* __restrict__ dst,
                                              int* __restrict__ cur_d,
                                              int* __restrict__ dl_src, int E) {
  int e = blockIdx.x * 256 + threadIdx.x;
  if (e >= E) return;
  int pd = atomicAdd(&cur_d[dst[e]], 1);
  dl_src[pd] = src[e];
}

// ---- pass1: per dst node, compute ev=exp(exp(cos)/TAU); EV seq store; DEN[src] atomic sum ----
__global__ __launch_bounds__(256) void gat_pre_k(const float* __restrict__ XL,
                                                 const float* __restrict__ SLI,
                                                 const float* __restrict__ XRN,
                                                 const int* __restrict__ off_d,
                                                 const int* __restrict__ dl_src,
                                                 float* __restrict__ EV,
                                                 float* __restrict__ DEN, int n) {
  int wv = threadIdx.x >> 6, lane = threadIdx.x & 63;
  int node = blockIdx.x * 4 + wv;
  if (node >= n) return;
  int q = lane >> 4, ql = lane & 15;
  int beg = off_d[node];
  int deg = off_d[node + 1] - beg;
  float4 xr = *(const float4*)&XRN[(size_t)node * 64 + ql * 4];
  for (int i0 = 0; i0 < deg; i0 += 4) {
    int i = i0 + q;
    if (i < deg) {
      int s = dl_src[beg + i];
      float4 xv = *(const float4*)&XL[(size_t)s * 64 + ql * 4];
      float p = xv.x * xr.x + xv.y * xr.y + xv.z * xr.z + xv.w * xr.w;
      p += __shfl_xor(p, 1, 16); p += __shfl_xor(p, 2, 16);
      p += __shfl_xor(p, 4, 16); p += __shfl_xor(p, 8, 16);
      if (ql == 0) {
        float ev = __expf(__expf(p * SLI[s]) * 4.0f);  // exp(v), v=exp(cos)/TAU
        EV[beg + i] = ev;
        unsafeAtomicAdd(&DEN[s], ev);
      }
    }
  }
}

// ---- pass2: per dst node, acc += (ev/den[s]) * xl[s]; one write per node ----
__global__ __launch_bounds__(256) void gat_dst_k(const float* __restrict__ XL,
                                                 const float* __restrict__ EV,
                                                 const float* __restrict__ DEN,
                                                 const int* __restrict__ off_d,
                                                 const int* __restrict__ dl_src,
                                                 float* __restrict__ AGG, int n) {
  int wv = threadIdx.x >> 6, lane = threadIdx.x & 63;
  int node = blockIdx.x * 4 + wv;
  if (node >= n) return;
  int q = lane >> 4, ql = lane & 15;
  int beg = off_d[node];
  int deg = off_d[node + 1] - beg;
  float4 acc = {0.f, 0.f, 0.f, 0.f};
  for (int i0 = 0; i0 < deg; i0 += 4) {
    int i = i0 + q;
    if (i < deg) {
      int s = dl_src[beg + i];
      float4 xv = *(const float4*)&XL[(size_t)s * 64 + ql * 4];
      float w = 0.f;
      if (ql == 0) w = EV[beg + i] / DEN[s];
      w = __shfl(w, 0, 16);
      acc.x += w * xv.x; acc.y += w * xv.y; acc.z += w * xv.z; acc.w += w * xv.w;
    }
  }
  acc.x += __shfl_xor(acc.x, 16); acc.y += __shfl_xor(acc.y, 16);
  acc.z += __shfl_xor(acc.z, 16); acc.w += __shfl_xor(acc.w, 16);
  acc.x += __shfl_xor(acc.x, 32); acc.y += __shfl_xor(acc.y, 32);
  acc.z += __shfl_xor(acc.z, 32); acc.w += __shfl_xor(acc.w, 32);
  if (q == 0) *(float4*)&AGG[(size_t)node * 64 + ql * 4] = acc;
}

extern "C" void kernel_launch(void* const* d_in, const int* in_sizes, int n_in,
                              void* d_out, int out_size, void* d_ws, size_t ws_size,
                              hipStream_t stream) {
  const int N = in_sizes[0] / IN_C;
  const int E = in_sizes[1] / 2;
  const int* ei  = (const int*)d_in[1];
  const int* src = ei;
  const int* dst = ei + E;

  // ---- workspace layout (8B-aligned chunks) ----
  char* wsb = (char*)d_ws;
  size_t o = 0;
  auto alloc = [&](size_t elems) { void* p = wsb + o; o += ((elems + 1) & ~1ull) * 4; return p; };
  int*    FLAG   = (int*)alloc(16);
  float*  WF     = (float*)alloc(60000);
  int*    CNT_D  = (int*)alloc(N);
  int*    OFF_D  = (int*)alloc(N + 1);
  int*    CUR_D  = (int*)alloc(N);
  int*    PART   = (int*)alloc(256);
  int*    DL_SRC = (int*)alloc(E);
  float*  EV     = (float*)alloc(E);
  float*  DEN    = (float*)alloc(N);
  float*  SLI    = (float*)alloc(N);
  float*  bufA   = (float*)alloc((size_t)N * 128);  // XF -> XRN(upper) / OUTF(lower)
  float*  bufB   = (float*)alloc((size_t)N * 128);  // H0 -> AGG1/Hb/T | AGG2/H2
  float*  bufC   = (float*)alloc((size_t)N * 64);   // XL raw

  float* XF  = bufA;
  float* XRN = bufA + (size_t)N * 64;
  float* H0  = bufB;
  float* B1  = bufB;                    // AGG1 / Hb / T
  float* B2  = bufB + (size_t)N * 64;   // AGG2 / H2
  float* XL  = bufC;

  dim3 blk(256);
  auto nblk = [](long total, int per) { return dim3((unsigned)((total + per - 1) / per)); };

  // ---- dtype detect + convert ----
  detect_k<<<1, blk, 0, stream>>>((const unsigned short*)d_in[0], FLAG);
  cvt_k<<<nblk((long)N * 128, 256), blk, 0, stream>>>(d_in[0], XF, N * 128, FLAG);
  WArgs wa;
  int wtot = 0;
  float* wp[16];
  for (int i = 2; i < 16; i++) {
    wa.p[i - 2] = d_in[i];
    wa.off[i - 2] = wtot;
    wp[i] = WF + wtot;
    wtot += in_sizes[i];
  }
  wa.off[14] = wtot;
  cvtw_k<<<nblk(wtot, 256), blk, 0, stream>>>(wa, WF, FLAG, wtot);
  const float *W_in = wp[2], *b_in = wp[3], *Wl1 = wp[4], *Wr1 = wp[5],
              *bias1 = wp[6], *Wc1 = wp[7], *Wl2 = wp[8], *Wr2 = wp[9],
              *bias2 = wp[10], *Wc2 = wp[11], *W3 = wp[12], *b3 = wp[13],
              *W4 = wp[14], *b4 = wp[15];

  // ---- CSR build (dst side only; both GAT layers share the graph) ----
  hipMemsetAsync(CNT_D, 0, sizeof(int) * (size_t)N, stream);
  count_k<<<nblk(E, 256), blk, 0, stream>>>(dst, CNT_D, E);
  {
    int nb = (N + 2047) / 2048;
    scan_local_k<<<dim3(nb), blk, 0, stream>>>(CNT_D, OFF_D, PART, N);
    scan_add_k<<<dim3(nb), blk, 0, stream>>>(OFF_D, CUR_D, PART, nb, N);
  }
  fill_k<<<nblk(E, 256), blk, 0, stream>>>(src, dst, CUR_D, DL_SRC, E);

  // h0 = leaky(x @ W_in + b_in)
  lin_k<128, 128, 1, false, true, 0>
      <<<nblk(N, 16), blk, 0, stream>>>(XF, W_in, nullptr, b_in, H0, nullptr, N);

  // ---- GAT layer 1 ----
  lin_k<128, 64, 0, false, false, 3>   // XL raw -> bufC, SLI = 1/||row||
      <<<nblk(N, 32), blk, 0, stream>>>(H0, Wl1, nullptr, nullptr, XL, SLI, N);
  lin_k<128, 64, 0, false, false, 1>   // XRN normalized
      <<<nblk(N, 32), blk, 0, stream>>>(H0, Wr1, nullptr, nullptr, XRN, nullptr, N);
  hipMemsetAsync(DEN, 0, sizeof(float) * (size_t)N, stream);
  gat_pre_k<<<nblk(N, 4), blk, 0, stream>>>(XL, SLI, XRN, OFF_D, DL_SRC, EV, DEN, N);
  gat_dst_k<<<nblk(N, 4), blk, 0, stream>>>(XL, EV, DEN, OFF_D, DL_SRC, B1, N);
  lin_k<64, 64, 1, true, false, 0>
      <<<nblk(N, 32), blk, 0, stream>>>(B1, Wc1, bias1, nullptr, B1, nullptr, N);

  // ---- GAT layer 2 ----
  lin_k<64, 64, 0, false, false, 3>
      <<<nblk(N, 32), blk, 0, stream>>>(B1, Wl2, nullptr, nullptr, XL, SLI, N);
  lin_k<64, 64, 0, false, false, 1>
      <<<nblk(N, 32), blk, 0, stream>>>(B1, Wr2, nullptr, nullptr, XRN, nullptr, N);
  hipMemsetAsync(DEN, 0, sizeof(float) * (size_t)N, stream);
  gat_pre_k<<<nblk(N, 4), blk, 0, stream>>>(XL, SLI, XRN, OFF_D, DL_SRC, EV, DEN, N);
  gat_dst_k<<<nblk(N, 4), blk, 0, stream>>>(XL, EV, DEN, OFF_D, DL_SRC, B2, N);
  lin_k<64, 64, 1, true, false, 0>
      <<<nblk(N, 32), blk, 0, stream>>>(B2, Wc2, bias2, nullptr, B2, nullptr, N);

  // ---- head ----
  lin_k<64, 64, 2, false, true, 0>
      <<<nblk(N, 32), blk, 0, stream>>>(B2, W3, nullptr, b3, B1, nullptr, N);
  lin_k<64, 32, 0, false, true, 0>
      <<<nblk(N, 64), blk, 0, stream>>>(B1, W4, nullptr, b4, bufA, nullptr, N);
  out_k<<<nblk((long)N * 32, 256), blk, 0, stream>>>(bufA, d_out, N * 32, FLAG);
}

// Round 7
// 1302.815 us; speedup vs baseline: 1.1994x; 1.0665x over previous
//
#include <hip/hip_runtime.h>
#include <hip/hip_bf16.h>

typedef __hip_bfloat16 bf16;

#define IN_C 128

// ---- dtype detection: flag=1 if buffer is bf16, 0 if float32 ----
__global__ __launch_bounds__(256) void detect_k(const unsigned short* __restrict__ xb,
                                                int* __restrict__ flag) {
  __shared__ int s_sane;
  if (threadIdx.x == 0) s_sane = 0;
  __syncthreads();
  int sane = 0;
  for (int i = threadIdx.x; i < 4096; i += 256) {
    unsigned short h = xb[2 * i];
    int e = (h >> 7) & 0xFF;
    if (e >= 100 && e <= 150) sane++;
  }
  atomicAdd(&s_sane, sane);
  __syncthreads();
  if (threadIdx.x == 0) *flag = (s_sane > 3072) ? 1 : 0;
}

__global__ __launch_bounds__(256) void cvt_k(const void* __restrict__ in,
                                             float* __restrict__ out, int n,
                                             const int* __restrict__ flag) {
  int i = blockIdx.x * 256 + threadIdx.x;
  if (i >= n) return;
  if (*flag) out[i] = __bfloat162float(((const bf16*)in)[i]);
  else       out[i] = ((const float*)in)[i];
}

struct WArgs { const void* p[14]; int off[15]; };
__global__ __launch_bounds__(256) void cvtw_k(WArgs a, float* __restrict__ out,
                                              const int* __restrict__ flag, int total) {
  int i = blockIdx.x * 256 + threadIdx.x;
  if (i >= total) return;
  int s = 0;
#pragma unroll
  for (int j = 1; j < 14; j++) if (i >= a.off[j]) s = j;
  int loc = i - a.off[s];
  if (*flag) out[i] = __bfloat162float(((const bf16*)a.p[s])[loc]);
  else       out[i] = ((const float*)a.p[s])[loc];
}

__global__ __launch_bounds__(256) void out_k(const float* __restrict__ src,
                                             void* __restrict__ out, int n,
                                             const int* __restrict__ flag) {
  int i = blockIdx.x * 256 + threadIdx.x;
  if (i >= n) return;
  float v = src[i];
  if (*flag) ((bf16*)out)[i] = __float2bfloat16(v);
  else       ((float*)out)[i] = v;
}

// out[n,C] = act((x[n,K]+preb) @ W[K,C] + postb)
// ACT: 0 none, 1 leaky(0.01), 2 relu.
// NRM: 0 none; 1 out=f32 normalized rows; 4 out=bf16 raw rows, out2=bf16 normalized rows (C==64)
template <int K, int C, int ACT, bool PREB, bool POSTB, int NRM>
__global__ __launch_bounds__(256) void lin_k(const float* __restrict__ x,
                                             const float* __restrict__ W,
                                             const float* __restrict__ preb,
                                             const float* __restrict__ postb,
                                             float* __restrict__ out,
                                             float* __restrict__ out2, int n) {
  constexpr int G = 256 / C;
  constexpr int R = 8;
  constexpr int RPB = G * R;
  __shared__ float xs[RPB * K];
  const int tid = threadIdx.x;
  const int row0 = blockIdx.x * RPB;
  for (int i = tid; i < RPB * K; i += 256) {
    int r = i / K, k = i - r * K;
    int row = row0 + r;
    float v = 0.f;
    if (row < n) v = x[(size_t)row * K + k];
    if (PREB) v += preb[k];
    xs[i] = v;
  }
  __syncthreads();
  const int c = tid % C;
  const int g = tid / C;
  float acc[R];
#pragma unroll
  for (int r = 0; r < R; r++) acc[r] = 0.f;
  const float* xg = xs + g * R * K;
  for (int k = 0; k < K; k += 4) {
    float w0 = W[(k + 0) * C + c];
    float w1 = W[(k + 1) * C + c];
    float w2 = W[(k + 2) * C + c];
    float w3 = W[(k + 3) * C + c];
#pragma unroll
    for (int r = 0; r < R; r++) {
      const float* xp = xg + r * K + k;
      acc[r] += xp[0] * w0;
      acc[r] += xp[1] * w1;
      acc[r] += xp[2] * w2;
      acc[r] += xp[3] * w3;
    }
  }
  float pb = POSTB ? postb[c] : 0.f;
#pragma unroll
  for (int r = 0; r < R; r++) {
    float v = acc[r] + pb;
    if (ACT == 1) v = (v >= 0.f) ? v : 0.01f * v;
    if (ACT == 2) v = (v > 0.f) ? v : 0.f;
    int row = row0 + g * R + r;
    if (NRM == 0) {
      if (row < n) out[(size_t)row * C + c] = v;
    } else {
      // C==64: one wave holds the full row -> shfl reduce sumsq
      float ss = v * v;
#pragma unroll
      for (int o = 32; o > 0; o >>= 1) ss += __shfl_xor(ss, o);
      float inv = 1.0f / fmaxf(sqrtf(ss), 1e-12f);
      if (row < n) {
        if (NRM == 1) {
          out[(size_t)row * C + c] = v * inv;
        } else {  // NRM == 4
          ((bf16*)out)[(size_t)row * C + c]  = __float2bfloat16(v);
          ((bf16*)out2)[(size_t)row * C + c] = __float2bfloat16(v * inv);
        }
      }
    }
  }
}

// ---- CSR build (dst side only) ----
__global__ __launch_bounds__(256) void count_k(const int* __restrict__ dst,
                                               int* __restrict__ cnt_d, int E) {
  int e = blockIdx.x * 256 + threadIdx.x;
  if (e >= E) return;
  atomicAdd(&cnt_d[dst[e]], 1);
}

// hierarchical exclusive scan, 2048 elems/block
__global__ __launch_bounds__(256) void scan_local_k(const int* __restrict__ cnt,
                                                    int* __restrict__ off,
                                                    int* __restrict__ part, int n) {
  __shared__ int sd[256];
  int t = threadIdx.x;
  int base = blockIdx.x * 2048 + t * 8;
  int v[8], s = 0;
#pragma unroll
  for (int j = 0; j < 8; j++) {
    int idx = base + j;
    v[j] = (idx < n) ? cnt[idx] : 0;
    s += v[j];
  }
  sd[t] = s;
  __syncthreads();
  for (int o = 1; o < 256; o <<= 1) {
    int x = (t >= o) ? sd[t - o] : 0;
    __syncthreads();
    sd[t] += x;
    __syncthreads();
  }
  int excl = sd[t] - s;
  if (t == 255) part[blockIdx.x] = sd[255];
  int run = excl;
#pragma unroll
  for (int j = 0; j < 8; j++) {
    int idx = base + j;
    if (idx < n) off[idx] = run;
    run += v[j];
  }
}

__global__ __launch_bounds__(256) void scan_add_k(int* __restrict__ off,
                                                  int* __restrict__ cur,
                                                  const int* __restrict__ part,
                                                  int nb, int n) {
  __shared__ int s_pref;
  if (threadIdx.x == 0) {
    int s = 0;
    for (int i = 0; i < (int)blockIdx.x; i++) s += part[i];
    s_pref = s;
    if (blockIdx.x == 0) {
      int tot = 0;
      for (int i = 0; i < nb; i++) tot += part[i];
      off[n] = tot;
    }
  }
  __syncthreads();
  int pref = s_pref;
  int base = blockIdx.x * 2048 + threadIdx.x * 8;
#pragma unroll
  for (int j = 0; j < 8; j++) {
    int idx = base + j;
    if (idx < n) { int val = off[idx] + pref; off[idx] = val; cur[idx] = val; }
  }
}

// fill: single scatter (dst-CSR only), nontemporal to dodge write-allocate
__global__ __launch_bounds__(256) void fill_k(const int* __restrict__ src,
                                              const int* __restrict__ dst,
                                              int* __restrict__ cur_d,
                                              int* __restrict__ dl_src, int E) {
  int e = blockIdx.x * 256 + threadIdx.x;
  if (e >= E) return;
  int pd = atomicAdd(&cur_d[dst[e]], 1);
  __builtin_nontemporal_store(src[e], &dl_src[pd]);
}

__device__ inline float4 bf4_to_f4(ushort4 h) {
  float4 f;
  f.x = __uint_as_float((unsigned)h.x << 16);
  f.y = __uint_as_float((unsigned)h.y << 16);
  f.z = __uint_as_float((unsigned)h.z << 16);
  f.w = __uint_as_float((unsigned)h.w << 16);
  return f;
}

// ---- pass1: per dst node, ev=exp(exp(cos)/TAU); EV seq store; DEN[src] atomic sum ----
// XLN: bf16 normalized rows (gather, 128B/edge); XRN: f32 normalized rows (per node)
__global__ __launch_bounds__(256) void gat_pre_k(const ushort4* __restrict__ XLN,
                                                 const float* __restrict__ XRN,
                                                 const int* __restrict__ off_d,
                                                 const int* __restrict__ dl_src,
                                                 float* __restrict__ EV,
                                                 float* __restrict__ DEN, int n) {
  int wv = threadIdx.x >> 6, lane = threadIdx.x & 63;
  int node = blockIdx.x * 4 + wv;
  if (node >= n) return;
  int q = lane >> 4, ql = lane & 15;
  int beg = off_d[node];
  int deg = off_d[node + 1] - beg;
  float4 xr = *(const float4*)&XRN[(size_t)node * 64 + ql * 4];
  for (int i0 = 0; i0 < deg; i0 += 4) {
    int i = i0 + q;
    if (i < deg) {
      int s = dl_src[beg + i];
      float4 xv = bf4_to_f4(XLN[(size_t)s * 16 + ql]);
      float p = xv.x * xr.x + xv.y * xr.y + xv.z * xr.z + xv.w * xr.w;
      p += __shfl_xor(p, 1, 16); p += __shfl_xor(p, 2, 16);
      p += __shfl_xor(p, 4, 16); p += __shfl_xor(p, 8, 16);
      if (ql == 0) {
        float ev = __expf(__expf(p) * 4.0f);  // exp(v), v=exp(cos)/TAU
        EV[beg + i] = ev;
        unsafeAtomicAdd(&DEN[s], ev);
      }
    }
  }
}

// ---- pass2: per dst node, acc += (ev/den[s]) * xlb[s]; one write per node ----
__global__ __launch_bounds__(256) void gat_dst_k(const ushort4* __restrict__ XLB,
                                                 const float* __restrict__ EV,
                                                 const float* __restrict__ DEN,
                                                 const int* __restrict__ off_d,
                                                 const int* __restrict__ dl_src,
                                                 float* __restrict__ AGG, int n) {
  int wv = threadIdx.x >> 6, lane = threadIdx.x & 63;
  int node = blockIdx.x * 4 + wv;
  if (node >= n) return;
  int q = lane >> 4, ql = lane & 15;
  int beg = off_d[node];
  int deg = off_d[node + 1] - beg;
  float4 acc = {0.f, 0.f, 0.f, 0.f};
  for (int i0 = 0; i0 < deg; i0 += 4) {
    int i = i0 + q;
    if (i < deg) {
      int s = dl_src[beg + i];
      float4 xv = bf4_to_f4(XLB[(size_t)s * 16 + ql]);
      float w = 0.f;
      if (ql == 0) w = EV[beg + i] / DEN[s];
      w = __shfl(w, 0, 16);
      acc.x += w * xv.x; acc.y += w * xv.y; acc.z += w * xv.z; acc.w += w * xv.w;
    }
  }
  acc.x += __shfl_xor(acc.x, 16); acc.y += __shfl_xor(acc.y, 16);
  acc.z += __shfl_xor(acc.z, 16); acc.w += __shfl_xor(acc.w, 16);
  acc.x += __shfl_xor(acc.x, 32); acc.y += __shfl_xor(acc.y, 32);
  acc.z += __shfl_xor(acc.z, 32); acc.w += __shfl_xor(acc.w, 32);
  if (q == 0) *(float4*)&AGG[(size_t)node * 64 + ql * 4] = acc;
}

extern "C" void kernel_launch(void* const* d_in, const int* in_sizes, int n_in,
                              void* d_out, int out_size, void* d_ws, size_t ws_size,
                              hipStream_t stream) {
  const int N = in_sizes[0] / IN_C;
  const int E = in_sizes[1] / 2;
  const int* ei  = (const int*)d_in[1];
  const int* src = ei;
  const int* dst = ei + E;

  // ---- workspace layout (8B-aligned chunks of 4B elems) ----
  char* wsb = (char*)d_ws;
  size_t o = 0;
  auto alloc = [&](size_t elems) { void* p = wsb + o; o += ((elems + 1) & ~1ull) * 4; return p; };
  int*     FLAG   = (int*)alloc(16);
  float*   WF     = (float*)alloc(60000);
  int*     CNT_D  = (int*)alloc(N);
  int*     OFF_D  = (int*)alloc(N + 1);
  int*     CUR_D  = (int*)alloc(N);
  int*     PART   = (int*)alloc(256);
  int*     DL_SRC = (int*)alloc(E);
  float*   EV     = (float*)alloc(E);
  float*   DEN    = (float*)alloc(N);
  ushort4* XLB    = (ushort4*)alloc((size_t)N * 32);  // N x 64 bf16 raw xl rows
  ushort4* XLN    = (ushort4*)alloc((size_t)N * 32);  // N x 64 bf16 normalized xl rows
  float*   bufA   = (float*)alloc((size_t)N * 128);   // XF -> XRN(upper) / OUTF(lower)
  float*   bufB   = (float*)alloc((size_t)N * 128);   // H0 -> AGG1/Hb/T | AGG2/H2

  float* XF  = bufA;
  float* XRN = bufA + (size_t)N * 64;
  float* H0  = bufB;
  float* B1  = bufB;                    // AGG1 / Hb / T
  float* B2  = bufB + (size_t)N * 64;   // AGG2 / H2

  dim3 blk(256);
  auto nblk = [](long total, int per) { return dim3((unsigned)((total + per - 1) / per)); };

  // ---- dtype detect + convert ----
  detect_k<<<1, blk, 0, stream>>>((const unsigned short*)d_in[0], FLAG);
  cvt_k<<<nblk((long)N * 128, 256), blk, 0, stream>>>(d_in[0], XF, N * 128, FLAG);
  WArgs wa;
  int wtot = 0;
  float* wp[16];
  for (int i = 2; i < 16; i++) {
    wa.p[i - 2] = d_in[i];
    wa.off[i - 2] = wtot;
    wp[i] = WF + wtot;
    wtot += in_sizes[i];
  }
  wa.off[14] = wtot;
  cvtw_k<<<nblk(wtot, 256), blk, 0, stream>>>(wa, WF, FLAG, wtot);
  const float *W_in = wp[2], *b_in = wp[3], *Wl1 = wp[4], *Wr1 = wp[5],
              *bias1 = wp[6], *Wc1 = wp[7], *Wl2 = wp[8], *Wr2 = wp[9],
              *bias2 = wp[10], *Wc2 = wp[11], *W3 = wp[12], *b3 = wp[13],
              *W4 = wp[14], *b4 = wp[15];

  // ---- CSR build (dst side only; both GAT layers share the graph) ----
  hipMemsetAsync(CNT_D, 0, sizeof(int) * (size_t)N, stream);
  count_k<<<nblk(E, 256), blk, 0, stream>>>(dst, CNT_D, E);
  {
    int nb = (N + 2047) / 2048;
    scan_local_k<<<dim3(nb), blk, 0, stream>>>(CNT_D, OFF_D, PART, N);
    scan_add_k<<<dim3(nb), blk, 0, stream>>>(OFF_D, CUR_D, PART, nb, N);
  }
  fill_k<<<nblk(E, 256), blk, 0, stream>>>(src, dst, CUR_D, DL_SRC, E);

  // h0 = leaky(x @ W_in + b_in)
  lin_k<128, 128, 1, false, true, 0>
      <<<nblk(N, 16), blk, 0, stream>>>(XF, W_in, nullptr, b_in, H0, nullptr, N);

  // ---- GAT layer 1 ----
  lin_k<128, 64, 0, false, false, 4>   // XLB(raw bf16) + XLN(normalized bf16)
      <<<nblk(N, 32), blk, 0, stream>>>(H0, Wl1, nullptr, nullptr, (float*)XLB, (float*)XLN, N);
  lin_k<128, 64, 0, false, false, 1>   // XRN normalized f32
      <<<nblk(N, 32), blk, 0, stream>>>(H0, Wr1, nullptr, nullptr, XRN, nullptr, N);
  hipMemsetAsync(DEN, 0, sizeof(float) * (size_t)N, stream);
  gat_pre_k<<<nblk(N, 4), blk, 0, stream>>>(XLN, XRN, OFF_D, DL_SRC, EV, DEN, N);
  gat_dst_k<<<nblk(N, 4), blk, 0, stream>>>(XLB, EV, DEN, OFF_D, DL_SRC, B1, N);
  lin_k<64, 64, 1, true, false, 0>
      <<<nblk(N, 32), blk, 0, stream>>>(B1, Wc1, bias1, nullptr, B1, nullptr, N);

  // ---- GAT layer 2 ----
  lin_k<64, 64, 0, false, false, 4>
      <<<nblk(N, 32), blk, 0, stream>>>(B1, Wl2, nullptr, nullptr, (float*)XLB, (float*)XLN, N);
  lin_k<64, 64, 0, false, false, 1>
      <<<nblk(N, 32), blk, 0, stream>>>(B1, Wr2, nullptr, nullptr, XRN, nullptr, N);
  hipMemsetAsync(DEN, 0, sizeof(float) * (size_t)N, stream);
  gat_pre_k<<<nblk(N, 4), blk, 0, stream>>>(XLN, XRN, OFF_D, DL_SRC, EV, DEN, N);
  gat_dst_k<<<nblk(N, 4), blk, 0, stream>>>(XLB, EV, DEN, OFF_D, DL_SRC, B2, N);
  lin_k<64, 64, 1, true, false, 0>
      <<<nblk(N, 32), blk, 0, stream>>>(B2, Wc2, bias2, nullptr, B2, nullptr, N);

  // ---- head ----
  lin_k<64, 64, 2, false, true, 0>
      <<<nblk(N, 32), blk, 0, stream>>>(B2, W3, nullptr, b3, B1, nullptr, N);
  lin_k<64, 32, 0, false, true, 0>
      <<<nblk(N, 64), blk, 0, stream>>>(B1, W4, nullptr, b4, bufA, nullptr, N);
  out_k<<<nblk((long)N * 32, 256), blk, 0, stream>>>(bufA, d_out, N * 32, FLAG);
}

// Round 8
// 1195.246 us; speedup vs baseline: 1.3073x; 1.0900x over previous
//
#include <hip/hip_runtime.h>
#include <hip/hip_bf16.h>

typedef __hip_bfloat16 bf16;

#define IN_C 128

// ---- dtype detection: flag=1 if buffer is bf16, 0 if float32 ----
__global__ __launch_bounds__(256) void detect_k(const unsigned short* __restrict__ xb,
                                                int* __restrict__ flag) {
  __shared__ int s_sane;
  if (threadIdx.x == 0) s_sane = 0;
  __syncthreads();
  int sane = 0;
  for (int i = threadIdx.x; i < 4096; i += 256) {
    unsigned short h = xb[2 * i];
    int e = (h >> 7) & 0xFF;
    if (e >= 100 && e <= 150) sane++;
  }
  atomicAdd(&s_sane, sane);
  __syncthreads();
  if (threadIdx.x == 0) *flag = (s_sane > 3072) ? 1 : 0;
}

__global__ __launch_bounds__(256) void cvt_k(const void* __restrict__ in,
                                             float* __restrict__ out, int n,
                                             const int* __restrict__ flag) {
  int i = blockIdx.x * 256 + threadIdx.x;
  if (i >= n) return;
  if (*flag) out[i] = __bfloat162float(((const bf16*)in)[i]);
  else       out[i] = ((const float*)in)[i];
}

struct WArgs { const void* p[14]; int off[15]; };
__global__ __launch_bounds__(256) void cvtw_k(WArgs a, float* __restrict__ out,
                                              const int* __restrict__ flag, int total) {
  int i = blockIdx.x * 256 + threadIdx.x;
  if (i >= total) return;
  int s = 0;
#pragma unroll
  for (int j = 1; j < 14; j++) if (i >= a.off[j]) s = j;
  int loc = i - a.off[s];
  if (*flag) out[i] = __bfloat162float(((const bf16*)a.p[s])[loc]);
  else       out[i] = ((const float*)a.p[s])[loc];
}

__global__ __launch_bounds__(256) void out_k(const float* __restrict__ src,
                                             void* __restrict__ out, int n,
                                             const int* __restrict__ flag) {
  int i = blockIdx.x * 256 + threadIdx.x;
  if (i >= n) return;
  float v = src[i];
  if (*flag) ((bf16*)out)[i] = __float2bfloat16(v);
  else       ((float*)out)[i] = v;
}

// out[n,C] = act((x[n,K]+preb) @ W[K,C] + postb)
// ACT: 0 none, 1 leaky(0.01), 2 relu.
// NRM: 0 none; 1 out=f32 normalized rows; 4 out=bf16 raw rows, out2=bf16 normalized rows (C==64)
template <int K, int C, int ACT, bool PREB, bool POSTB, int NRM>
__global__ __launch_bounds__(256) void lin_k(const float* __restrict__ x,
                                             const float* __restrict__ W,
                                             const float* __restrict__ preb,
                                             const float* __restrict__ postb,
                                             float* __restrict__ out,
                                             float* __restrict__ out2, int n) {
  constexpr int G = 256 / C;
  constexpr int R = 8;
  constexpr int RPB = G * R;
  __shared__ float xs[RPB * K];
  const int tid = threadIdx.x;
  const int row0 = blockIdx.x * RPB;
  for (int i = tid; i < RPB * K; i += 256) {
    int r = i / K, k = i - r * K;
    int row = row0 + r;
    float v = 0.f;
    if (row < n) v = x[(size_t)row * K + k];
    if (PREB) v += preb[k];
    xs[i] = v;
  }
  __syncthreads();
  const int c = tid % C;
  const int g = tid / C;
  float acc[R];
#pragma unroll
  for (int r = 0; r < R; r++) acc[r] = 0.f;
  const float* xg = xs + g * R * K;
  for (int k = 0; k < K; k += 4) {
    float w0 = W[(k + 0) * C + c];
    float w1 = W[(k + 1) * C + c];
    float w2 = W[(k + 2) * C + c];
    float w3 = W[(k + 3) * C + c];
#pragma unroll
    for (int r = 0; r < R; r++) {
      const float* xp = xg + r * K + k;
      acc[r] += xp[0] * w0;
      acc[r] += xp[1] * w1;
      acc[r] += xp[2] * w2;
      acc[r] += xp[3] * w3;
    }
  }
  float pb = POSTB ? postb[c] : 0.f;
#pragma unroll
  for (int r = 0; r < R; r++) {
    float v = acc[r] + pb;
    if (ACT == 1) v = (v >= 0.f) ? v : 0.01f * v;
    if (ACT == 2) v = (v > 0.f) ? v : 0.f;
    int row = row0 + g * R + r;
    if (NRM == 0) {
      if (row < n) out[(size_t)row * C + c] = v;
    } else {
      float ss = v * v;
#pragma unroll
      for (int o = 32; o > 0; o >>= 1) ss += __shfl_xor(ss, o);
      float inv = 1.0f / fmaxf(sqrtf(ss), 1e-12f);
      if (row < n) {
        if (NRM == 1) {
          out[(size_t)row * C + c] = v * inv;
        } else {  // NRM == 4
          ((bf16*)out)[(size_t)row * C + c]  = __float2bfloat16(v);
          ((bf16*)out2)[(size_t)row * C + c] = __float2bfloat16(v * inv);
        }
      }
    }
  }
}

// ---- CSR build (dst side only) ----
__global__ __launch_bounds__(256) void count_k(const int* __restrict__ dst,
                                               int* __restrict__ cnt_d, int E) {
  int e = blockIdx.x * 256 + threadIdx.x;
  if (e >= E) return;
  atomicAdd(&cnt_d[dst[e]], 1);
}

__global__ __launch_bounds__(256) void scan_local_k(const int* __restrict__ cnt,
                                                    int* __restrict__ off,
                                                    int* __restrict__ part, int n) {
  __shared__ int sd[256];
  int t = threadIdx.x;
  int base = blockIdx.x * 2048 + t * 8;
  int v[8], s = 0;
#pragma unroll
  for (int j = 0; j < 8; j++) {
    int idx = base + j;
    v[j] = (idx < n) ? cnt[idx] : 0;
    s += v[j];
  }
  sd[t] = s;
  __syncthreads();
  for (int o = 1; o < 256; o <<= 1) {
    int x = (t >= o) ? sd[t - o] : 0;
    __syncthreads();
    sd[t] += x;
    __syncthreads();
  }
  int excl = sd[t] - s;
  if (t == 255) part[blockIdx.x] = sd[255];
  int run = excl;
#pragma unroll
  for (int j = 0; j < 8; j++) {
    int idx = base + j;
    if (idx < n) off[idx] = run;
    run += v[j];
  }
}

__global__ __launch_bounds__(256) void scan_add_k(int* __restrict__ off,
                                                  int* __restrict__ cur,
                                                  const int* __restrict__ part,
                                                  int nb, int n) {
  __shared__ int s_pref;
  if (threadIdx.x == 0) {
    int s = 0;
    for (int i = 0; i < (int)blockIdx.x; i++) s += part[i];
    s_pref = s;
    if (blockIdx.x == 0) {
      int tot = 0;
      for (int i = 0; i < nb; i++) tot += part[i];
      off[n] = tot;
    }
  }
  __syncthreads();
  int pref = s_pref;
  int base = blockIdx.x * 2048 + threadIdx.x * 8;
#pragma unroll
  for (int j = 0; j < 8; j++) {
    int idx = base + j;
    if (idx < n) { int val = off[idx] + pref; off[idx] = val; cur[idx] = val; }
  }
}

// fill: XCD-partitioned. Group k = blockIdx&7 handles dst in [k*N/8,(k+1)*N/8):
// its dl_src writes land in one contiguous ~E/8 slice -> lines accumulate all
// their writes in that XCD's L2 before eviction.
__global__ __launch_bounds__(256) void fill_k(const int* __restrict__ src,
                                              const int* __restrict__ dst,
                                              int* __restrict__ cur_d,
                                              int* __restrict__ dl_src, int E, int N) {
  int part = blockIdx.x & 7;
  int lo = (int)(((long)part * N) >> 3);
  int hi = (int)((((long)part + 1) * N) >> 3);
  int tid = (blockIdx.x >> 3) * 256 + threadIdx.x;
  int stride = (gridDim.x >> 3) * 256;
  for (int e = tid; e < E; e += stride) {
    int d = dst[e];
    if (d < lo || d >= hi) continue;
    int pd = atomicAdd(&cur_d[d], 1);
    dl_src[pd] = src[e];
  }
}

// bf16x8 row fragment (uint4 = 8 bf16) dot with 8 f32
__device__ inline float dot8(uint4 h, float4 r0, float4 r1) {
  float p;
  p  = __uint_as_float(h.x << 16) * r0.x + __uint_as_float(h.x & 0xffff0000u) * r0.y;
  p += __uint_as_float(h.y << 16) * r0.z + __uint_as_float(h.y & 0xffff0000u) * r0.w;
  p += __uint_as_float(h.z << 16) * r1.x + __uint_as_float(h.z & 0xffff0000u) * r1.y;
  p += __uint_as_float(h.w << 16) * r1.z + __uint_as_float(h.w & 0xffff0000u) * r1.w;
  return p;
}

__device__ inline void fma8(uint4 h, float w, float4& a0, float4& a1) {
  a0.x += w * __uint_as_float(h.x << 16); a0.y += w * __uint_as_float(h.x & 0xffff0000u);
  a0.z += w * __uint_as_float(h.y << 16); a0.w += w * __uint_as_float(h.y & 0xffff0000u);
  a1.x += w * __uint_as_float(h.z << 16); a1.y += w * __uint_as_float(h.z & 0xffff0000u);
  a1.z += w * __uint_as_float(h.w << 16); a1.w += w * __uint_as_float(h.w & 0xffff0000u);
}

// ---- pass1: 8 lanes/edge, 16 edges in flight/wave. ev=exp(exp(cos)/TAU);
//      EV seq store; DEN[src] atomic sum ----
__global__ __launch_bounds__(256) void gat_pre_k(const uint4* __restrict__ XLN,
                                                 const float* __restrict__ XRN,
                                                 const int* __restrict__ off_d,
                                                 const int* __restrict__ dl_src,
                                                 float* __restrict__ EV,
                                                 float* __restrict__ DEN, int n) {
  int wv = threadIdx.x >> 6, lane = threadIdx.x & 63;
  int node = blockIdx.x * 4 + wv;
  if (node >= n) return;
  int g = lane >> 3, gl = lane & 7;
  int beg = off_d[node];
  int deg = off_d[node + 1] - beg;
  if (deg <= 0) return;
  const float4* xrp = (const float4*)&XRN[(size_t)node * 64 + gl * 8];
  float4 xr0 = xrp[0], xr1 = xrp[1];
  for (int i0 = 0; i0 < deg; i0 += 16) {
    int iA = i0 + g, iB = iA + 8;
    int sA = dl_src[beg + ((iA < deg) ? iA : 0)];
    int sB = dl_src[beg + ((iB < deg) ? iB : 0)];
    uint4 hA = XLN[(size_t)sA * 8 + gl];
    uint4 hB = XLN[(size_t)sB * 8 + gl];
    float pA = dot8(hA, xr0, xr1);
    float pB = dot8(hB, xr0, xr1);
    pA += __shfl_xor(pA, 1, 8); pA += __shfl_xor(pA, 2, 8); pA += __shfl_xor(pA, 4, 8);
    pB += __shfl_xor(pB, 1, 8); pB += __shfl_xor(pB, 2, 8); pB += __shfl_xor(pB, 4, 8);
    if (gl == 0) {
      if (iA < deg) {
        float ev = __expf(__expf(pA) * 4.0f);
        EV[beg + iA] = ev;
        unsafeAtomicAdd(&DEN[sA], ev);
      }
      if (iB < deg) {
        float ev = __expf(__expf(pB) * 4.0f);
        EV[beg + iB] = ev;
        unsafeAtomicAdd(&DEN[sB], ev);
      }
    }
  }
}

// ---- pass2: 8 lanes/edge, acc += (ev/den[s]) * xlb[s]; one write per node ----
__global__ __launch_bounds__(256) void gat_dst_k(const uint4* __restrict__ XLB,
                                                 const float* __restrict__ EV,
                                                 const float* __restrict__ DEN,
                                                 const int* __restrict__ off_d,
                                                 const int* __restrict__ dl_src,
                                                 float* __restrict__ AGG, int n) {
  int wv = threadIdx.x >> 6, lane = threadIdx.x & 63;
  int node = blockIdx.x * 4 + wv;
  if (node >= n) return;
  int g = lane >> 3, gl = lane & 7;
  int beg = off_d[node];
  int deg = off_d[node + 1] - beg;
  float4 a0 = {0.f, 0.f, 0.f, 0.f}, a1 = {0.f, 0.f, 0.f, 0.f};
  for (int i0 = 0; i0 < deg; i0 += 16) {
    int iA = i0 + g, iB = iA + 8;
    int sA = dl_src[beg + ((iA < deg) ? iA : 0)];
    int sB = dl_src[beg + ((iB < deg) ? iB : 0)];
    uint4 hA = XLB[(size_t)sA * 8 + gl];
    uint4 hB = XLB[(size_t)sB * 8 + gl];
    float wA = 0.f, wB = 0.f;
    if (gl == 0) {
      if (iA < deg) wA = EV[beg + iA] / DEN[sA];
      if (iB < deg) wB = EV[beg + iB] / DEN[sB];
    }
    wA = __shfl(wA, 0, 8);
    wB = __shfl(wB, 0, 8);
    fma8(hA, wA, a0, a1);
    fma8(hB, wB, a0, a1);
  }
#pragma unroll
  for (int o = 8; o < 64; o <<= 1) {
    a0.x += __shfl_xor(a0.x, o); a0.y += __shfl_xor(a0.y, o);
    a0.z += __shfl_xor(a0.z, o); a0.w += __shfl_xor(a0.w, o);
    a1.x += __shfl_xor(a1.x, o); a1.y += __shfl_xor(a1.y, o);
    a1.z += __shfl_xor(a1.z, o); a1.w += __shfl_xor(a1.w, o);
  }
  if (g == 0) {
    *(float4*)&AGG[(size_t)node * 64 + gl * 8]     = a0;
    *(float4*)&AGG[(size_t)node * 64 + gl * 8 + 4] = a1;
  }
}

extern "C" void kernel_launch(void* const* d_in, const int* in_sizes, int n_in,
                              void* d_out, int out_size, void* d_ws, size_t ws_size,
                              hipStream_t stream) {
  const int N = in_sizes[0] / IN_C;
  const int E = in_sizes[1] / 2;
  const int* ei  = (const int*)d_in[1];
  const int* src = ei;
  const int* dst = ei + E;

  // ---- workspace layout (16B-aligned chunks of 4B elems) ----
  char* wsb = (char*)d_ws;
  size_t o = 0;
  auto alloc = [&](size_t elems) { void* p = wsb + o; o += ((elems + 3) & ~3ull) * 4; return p; };
  int*   FLAG   = (int*)alloc(16);
  float* WF     = (float*)alloc(60000);
  int*   CNT_D  = (int*)alloc(N);
  int*   OFF_D  = (int*)alloc(N + 1);
  int*   CUR_D  = (int*)alloc(N);
  int*   PART   = (int*)alloc(256);
  int*   DL_SRC = (int*)alloc(E);
  float* EV     = (float*)alloc(E);
  float* DEN    = (float*)alloc(N);
  uint4* XLB    = (uint4*)alloc((size_t)N * 32);  // N x 64 bf16 raw xl rows
  uint4* XLN    = (uint4*)alloc((size_t)N * 32);  // N x 64 bf16 normalized xl rows
  float* bufA   = (float*)alloc((size_t)N * 128); // XF -> XRN(upper) / OUTF(lower)
  float* bufB   = (float*)alloc((size_t)N * 128); // H0 -> AGG1/Hb/T | AGG2/H2

  float* XF  = bufA;
  float* XRN = bufA + (size_t)N * 64;
  float* H0  = bufB;
  float* B1  = bufB;
  float* B2  = bufB + (size_t)N * 64;

  dim3 blk(256);
  auto nblk = [](long total, int per) { return dim3((unsigned)((total + per - 1) / per)); };

  // ---- dtype detect + convert ----
  detect_k<<<1, blk, 0, stream>>>((const unsigned short*)d_in[0], FLAG);
  cvt_k<<<nblk((long)N * 128, 256), blk, 0, stream>>>(d_in[0], XF, N * 128, FLAG);
  WArgs wa;
  int wtot = 0;
  float* wp[16];
  for (int i = 2; i < 16; i++) {
    wa.p[i - 2] = d_in[i];
    wa.off[i - 2] = wtot;
    wp[i] = WF + wtot;
    wtot += in_sizes[i];
  }
  wa.off[14] = wtot;
  cvtw_k<<<nblk(wtot, 256), blk, 0, stream>>>(wa, WF, FLAG, wtot);
  const float *W_in = wp[2], *b_in = wp[3], *Wl1 = wp[4], *Wr1 = wp[5],
              *bias1 = wp[6], *Wc1 = wp[7], *Wl2 = wp[8], *Wr2 = wp[9],
              *bias2 = wp[10], *Wc2 = wp[11], *W3 = wp[12], *b3 = wp[13],
              *W4 = wp[14], *b4 = wp[15];

  // ---- CSR build (dst side only; both GAT layers share the graph) ----
  hipMemsetAsync(CNT_D, 0, sizeof(int) * (size_t)N, stream);
  count_k<<<nblk(E, 256), blk, 0, stream>>>(dst, CNT_D, E);
  {
    int nb = (N + 2047) / 2048;
    scan_local_k<<<dim3(nb), blk, 0, stream>>>(CNT_D, OFF_D, PART, N);
    scan_add_k<<<dim3(nb), blk, 0, stream>>>(OFF_D, CUR_D, PART, nb, N);
  }
  fill_k<<<dim3(2048), blk, 0, stream>>>(src, dst, CUR_D, DL_SRC, E, N);

  // h0 = leaky(x @ W_in + b_in)
  lin_k<128, 128, 1, false, true, 0>
      <<<nblk(N, 16), blk, 0, stream>>>(XF, W_in, nullptr, b_in, H0, nullptr, N);

  // ---- GAT layer 1 ----
  lin_k<128, 64, 0, false, false, 4>
      <<<nblk(N, 32), blk, 0, stream>>>(H0, Wl1, nullptr, nullptr, (float*)XLB, (float*)XLN, N);
  lin_k<128, 64, 0, false, false, 1>
      <<<nblk(N, 32), blk, 0, stream>>>(H0, Wr1, nullptr, nullptr, XRN, nullptr, N);
  hipMemsetAsync(DEN, 0, sizeof(float) * (size_t)N, stream);
  gat_pre_k<<<nblk(N, 4), blk, 0, stream>>>(XLN, XRN, OFF_D, DL_SRC, EV, DEN, N);
  gat_dst_k<<<nblk(N, 4), blk, 0, stream>>>(XLB, EV, DEN, OFF_D, DL_SRC, B1, N);
  lin_k<64, 64, 1, true, false, 0>
      <<<nblk(N, 32), blk, 0, stream>>>(B1, Wc1, bias1, nullptr, B1, nullptr, N);

  // ---- GAT layer 2 ----
  lin_k<64, 64, 0, false, false, 4>
      <<<nblk(N, 32), blk, 0, stream>>>(B1, Wl2, nullptr, nullptr, (float*)XLB, (float*)XLN, N);
  lin_k<64, 64, 0, false, false, 1>
      <<<nblk(N, 32), blk, 0, stream>>>(B1, Wr2, nullptr, nullptr, XRN, nullptr, N);
  hipMemsetAsync(DEN, 0, sizeof(float) * (size_t)N, stream);
  gat_pre_k<<<nblk(N, 4), blk, 0, stream>>>(XLN, XRN, OFF_D, DL_SRC, EV, DEN, N);
  gat_dst_k<<<nblk(N, 4), blk, 0, stream>>>(XLB, EV, DEN, OFF_D, DL_SRC, B2, N);
  lin_k<64, 64, 1, true, false, 0>
      <<<nblk(N, 32), blk, 0, stream>>>(B2, Wc2, bias2, nullptr, B2, nullptr, N);

  // ---- head ----
  lin_k<64, 64, 2, false, true, 0>
      <<<nblk(N, 32), blk, 0, stream>>>(B2, W3, nullptr, b3, B1, nullptr, N);
  lin_k<64, 32, 0, false, true, 0>
      <<<nblk(N, 64), blk, 0, stream>>>(B1, W4, nullptr, b4, bufA, nullptr, N);
  out_k<<<nblk((long)N * 32, 256), blk, 0, stream>>>(bufA, d_out, N * 32, FLAG);
}

// Round 9
// 987.845 us; speedup vs baseline: 1.5818x; 1.2100x over previous
//
#include <hip/hip_runtime.h>
#include <hip/hip_bf16.h>

typedef __hip_bfloat16 bf16;

#define IN_C 128

__device__ inline unsigned short f2bf(float f) {
  bf16 b = __float2bfloat16(f);
  return __builtin_bit_cast(unsigned short, b);
}

// ---- dtype detection: flag=1 if buffer is bf16, 0 if float32 ----
__global__ __launch_bounds__(256) void detect_k(const unsigned short* __restrict__ xb,
                                                int* __restrict__ flag) {
  __shared__ int s_sane;
  if (threadIdx.x == 0) s_sane = 0;
  __syncthreads();
  int sane = 0;
  for (int i = threadIdx.x; i < 4096; i += 256) {
    unsigned short h = xb[2 * i];
    int e = (h >> 7) & 0xFF;
    if (e >= 100 && e <= 150) sane++;
  }
  atomicAdd(&s_sane, sane);
  __syncthreads();
  if (threadIdx.x == 0) *flag = (s_sane > 3072) ? 1 : 0;
}

__global__ __launch_bounds__(256) void cvt_k(const void* __restrict__ in,
                                             float* __restrict__ out, int n,
                                             const int* __restrict__ flag) {
  int i = blockIdx.x * 256 + threadIdx.x;
  if (i >= n) return;
  if (*flag) out[i] = __bfloat162float(((const bf16*)in)[i]);
  else       out[i] = ((const float*)in)[i];
}

struct WArgs { const void* p[14]; int off[15]; };
__global__ __launch_bounds__(256) void cvtw_k(WArgs a, float* __restrict__ out,
                                              const int* __restrict__ flag, int total) {
  int i = blockIdx.x * 256 + threadIdx.x;
  if (i >= total) return;
  int s = 0;
#pragma unroll
  for (int j = 1; j < 14; j++) if (i >= a.off[j]) s = j;
  int loc = i - a.off[s];
  if (*flag) out[i] = __bfloat162float(((const bf16*)a.p[s])[loc]);
  else       out[i] = ((const float*)a.p[s])[loc];
}

__global__ __launch_bounds__(256) void out_k(const float* __restrict__ src,
                                             void* __restrict__ out, int n,
                                             const int* __restrict__ flag) {
  int i = blockIdx.x * 256 + threadIdx.x;
  if (i >= n) return;
  float v = src[i];
  if (*flag) ((bf16*)out)[i] = __float2bfloat16(v);
  else       ((float*)out)[i] = v;
}

// ---- register-tiled linear: out[n,C] = act((x[n,K]+preb) @ W[K,C] + postb) ----
// Each thread: R rows x 4 cols. ACT: 0 none, 1 leaky(0.01), 2 relu.
// NRM: 0 none; 1 out=f32 normalized rows; 4 out=bf16 raw rows, out2=bf16 normalized.
template <int K, int C, int R, int ACT, bool PREB, bool POSTB, int NRM>
__global__ __launch_bounds__(256, 4) void lin_k(const float* __restrict__ x,
                                                const float* __restrict__ W,
                                                const float* __restrict__ preb,
                                                const float* __restrict__ postb,
                                                float* __restrict__ out,
                                                float* __restrict__ out2, int n) {
  constexpr int CG  = C / 4;        // col-groups (threads per row-slice)
  constexpr int RG  = 256 / CG;     // row-groups
  constexpr int RPB = RG * R;       // rows per block
  __shared__ float xs[RPB * K];
  const int tid = threadIdx.x;
  const int row0 = blockIdx.x * RPB;

  // stage x (+preb) into LDS, float4-vectorized
  for (int i = tid; i < RPB * K / 4; i += 256) {
    int r4 = i / (K / 4);
    int kk = (i - r4 * (K / 4)) * 4;
    int row = row0 + r4;
    float4 v = make_float4(0.f, 0.f, 0.f, 0.f);
    if (row < n) v = *(const float4*)&x[(size_t)row * K + kk];
    if (PREB) {
      v.x += preb[kk]; v.y += preb[kk + 1]; v.z += preb[kk + 2]; v.w += preb[kk + 3];
    }
    *(float4*)&xs[r4 * K + kk] = v;
  }
  __syncthreads();

  const int cg = tid % CG;
  const int g  = tid / CG;
  const int c0 = cg * 4;

  float4 acc[R];
#pragma unroll
  for (int r = 0; r < R; r++) acc[r] = make_float4(0.f, 0.f, 0.f, 0.f);

  for (int k = 0; k < K; k += 4) {
    const float* wb = &W[(size_t)k * C + c0];
    float4 w0 = *(const float4*)(wb);
    float4 w1 = *(const float4*)(wb + C);
    float4 w2 = *(const float4*)(wb + 2 * C);
    float4 w3 = *(const float4*)(wb + 3 * C);
#pragma unroll
    for (int r = 0; r < R; r++) {
      float4 xv = *(const float4*)&xs[(g * R + r) * K + k];
      float4 a = acc[r];
      a.x = fmaf(xv.x, w0.x, a.x); a.y = fmaf(xv.x, w0.y, a.y);
      a.z = fmaf(xv.x, w0.z, a.z); a.w = fmaf(xv.x, w0.w, a.w);
      a.x = fmaf(xv.y, w1.x, a.x); a.y = fmaf(xv.y, w1.y, a.y);
      a.z = fmaf(xv.y, w1.z, a.z); a.w = fmaf(xv.y, w1.w, a.w);
      a.x = fmaf(xv.z, w2.x, a.x); a.y = fmaf(xv.z, w2.y, a.y);
      a.z = fmaf(xv.z, w2.z, a.z); a.w = fmaf(xv.z, w2.w, a.w);
      a.x = fmaf(xv.w, w3.x, a.x); a.y = fmaf(xv.w, w3.y, a.y);
      a.z = fmaf(xv.w, w3.z, a.z); a.w = fmaf(xv.w, w3.w, a.w);
      acc[r] = a;
    }
  }

  float4 pb = make_float4(0.f, 0.f, 0.f, 0.f);
  if (POSTB) pb = *(const float4*)&postb[c0];
#pragma unroll
  for (int r = 0; r < R; r++) {
    int row = row0 + g * R + r;
    float4 v = acc[r];
    v.x += pb.x; v.y += pb.y; v.z += pb.z; v.w += pb.w;
    if (ACT == 1) {
      v.x = (v.x >= 0.f) ? v.x : 0.01f * v.x; v.y = (v.y >= 0.f) ? v.y : 0.01f * v.y;
      v.z = (v.z >= 0.f) ? v.z : 0.01f * v.z; v.w = (v.w >= 0.f) ? v.w : 0.01f * v.w;
    }
    if (ACT == 2) {
      v.x = fmaxf(v.x, 0.f); v.y = fmaxf(v.y, 0.f);
      v.z = fmaxf(v.z, 0.f); v.w = fmaxf(v.w, 0.f);
    }
    if (NRM == 0) {
      if (row < n) *(float4*)&out[(size_t)row * C + c0] = v;
    } else {
      float ss = v.x * v.x + v.y * v.y + v.z * v.z + v.w * v.w;
#pragma unroll
      for (int o = 1; o < CG; o <<= 1) ss += __shfl_xor(ss, o, CG);
      float inv = 1.0f / fmaxf(sqrtf(ss), 1e-12f);
      if (row < n) {
        if (NRM == 1) {
          float4 vn = make_float4(v.x * inv, v.y * inv, v.z * inv, v.w * inv);
          *(float4*)&out[(size_t)row * C + c0] = vn;
        } else {  // NRM == 4
          ushort4 hr = make_ushort4(f2bf(v.x), f2bf(v.y), f2bf(v.z), f2bf(v.w));
          ushort4 hn = make_ushort4(f2bf(v.x * inv), f2bf(v.y * inv),
                                    f2bf(v.z * inv), f2bf(v.w * inv));
          *(ushort4*)((bf16*)out  + (size_t)row * C + c0) = hr;
          *(ushort4*)((bf16*)out2 + (size_t)row * C + c0) = hn;
        }
      }
    }
  }
}

// ---- CSR build (dst side only) ----
__global__ __launch_bounds__(256) void count_k(const int* __restrict__ dst,
                                               int* __restrict__ cnt_d, int E) {
  int e = blockIdx.x * 256 + threadIdx.x;
  if (e >= E) return;
  atomicAdd(&cnt_d[dst[e]], 1);
}

__global__ __launch_bounds__(256) void scan_local_k(const int* __restrict__ cnt,
                                                    int* __restrict__ off,
                                                    int* __restrict__ part, int n) {
  __shared__ int sd[256];
  int t = threadIdx.x;
  int base = blockIdx.x * 2048 + t * 8;
  int v[8], s = 0;
#pragma unroll
  for (int j = 0; j < 8; j++) {
    int idx = base + j;
    v[j] = (idx < n) ? cnt[idx] : 0;
    s += v[j];
  }
  sd[t] = s;
  __syncthreads();
  for (int o = 1; o < 256; o <<= 1) {
    int x = (t >= o) ? sd[t - o] : 0;
    __syncthreads();
    sd[t] += x;
    __syncthreads();
  }
  int excl = sd[t] - s;
  if (t == 255) part[blockIdx.x] = sd[255];
  int run = excl;
#pragma unroll
  for (int j = 0; j < 8; j++) {
    int idx = base + j;
    if (idx < n) off[idx] = run;
    run += v[j];
  }
}

__global__ __launch_bounds__(256) void scan_add_k(int* __restrict__ off,
                                                  int* __restrict__ cur,
                                                  const int* __restrict__ part,
                                                  int nb, int n) {
  __shared__ int s_pref;
  if (threadIdx.x == 0) {
    int s = 0;
    for (int i = 0; i < (int)blockIdx.x; i++) s += part[i];
    s_pref = s;
    if (blockIdx.x == 0) {
      int tot = 0;
      for (int i = 0; i < nb; i++) tot += part[i];
      off[n] = tot;
    }
  }
  __syncthreads();
  int pref = s_pref;
  int base = blockIdx.x * 2048 + threadIdx.x * 8;
#pragma unroll
  for (int j = 0; j < 8; j++) {
    int idx = base + j;
    if (idx < n) { int val = off[idx] + pref; off[idx] = val; cur[idx] = val; }
  }
}

// fill: XCD-partitioned (group k=blockIdx&7 handles dst slice k) -> dl_src writes
// land in one contiguous ~E/8 slice per partition, L2-resident.
__global__ __launch_bounds__(256) void fill_k(const int* __restrict__ src,
                                              const int* __restrict__ dst,
                                              int* __restrict__ cur_d,
                                              int* __restrict__ dl_src, int E, int N) {
  int part = blockIdx.x & 7;
  int lo = (int)(((long)part * N) >> 3);
  int hi = (int)((((long)part + 1) * N) >> 3);
  int tid = (blockIdx.x >> 3) * 256 + threadIdx.x;
  int stride = (gridDim.x >> 3) * 256;
  for (int e = tid; e < E; e += stride) {
    int d = dst[e];
    if (d < lo || d >= hi) continue;
    int pd = atomicAdd(&cur_d[d], 1);
    dl_src[pd] = src[e];
  }
}

__device__ inline float dot8(uint4 h, float4 r0, float4 r1) {
  float p;
  p  = __uint_as_float(h.x << 16) * r0.x + __uint_as_float(h.x & 0xffff0000u) * r0.y;
  p += __uint_as_float(h.y << 16) * r0.z + __uint_as_float(h.y & 0xffff0000u) * r0.w;
  p += __uint_as_float(h.z << 16) * r1.x + __uint_as_float(h.z & 0xffff0000u) * r1.y;
  p += __uint_as_float(h.w << 16) * r1.z + __uint_as_float(h.w & 0xffff0000u) * r1.w;
  return p;
}

__device__ inline void fma8(uint4 h, float w, float4& a0, float4& a1) {
  a0.x += w * __uint_as_float(h.x << 16); a0.y += w * __uint_as_float(h.x & 0xffff0000u);
  a0.z += w * __uint_as_float(h.y << 16); a0.w += w * __uint_as_float(h.y & 0xffff0000u);
  a1.x += w * __uint_as_float(h.z << 16); a1.y += w * __uint_as_float(h.z & 0xffff0000u);
  a1.z += w * __uint_as_float(h.w << 16); a1.w += w * __uint_as_float(h.w & 0xffff0000u);
}

// ---- pass1: 8 lanes/edge, 16 edges in flight/wave ----
__global__ __launch_bounds__(256) void gat_pre_k(const uint4* __restrict__ XLN,
                                                 const float* __restrict__ XRN,
                                                 const int* __restrict__ off_d,
                                                 const int* __restrict__ dl_src,
                                                 float* __restrict__ EV,
                                                 float* __restrict__ DEN, int n) {
  int wv = threadIdx.x >> 6, lane = threadIdx.x & 63;
  int node = blockIdx.x * 4 + wv;
  if (node >= n) return;
  int g = lane >> 3, gl = lane & 7;
  int beg = off_d[node];
  int deg = off_d[node + 1] - beg;
  if (deg <= 0) return;
  const float4* xrp = (const float4*)&XRN[(size_t)node * 64 + gl * 8];
  float4 xr0 = xrp[0], xr1 = xrp[1];
  for (int i0 = 0; i0 < deg; i0 += 16) {
    int iA = i0 + g, iB = iA + 8;
    int sA = dl_src[beg + ((iA < deg) ? iA : 0)];
    int sB = dl_src[beg + ((iB < deg) ? iB : 0)];
    uint4 hA = XLN[(size_t)sA * 8 + gl];
    uint4 hB = XLN[(size_t)sB * 8 + gl];
    float pA = dot8(hA, xr0, xr1);
    float pB = dot8(hB, xr0, xr1);
    pA += __shfl_xor(pA, 1, 8); pA += __shfl_xor(pA, 2, 8); pA += __shfl_xor(pA, 4, 8);
    pB += __shfl_xor(pB, 1, 8); pB += __shfl_xor(pB, 2, 8); pB += __shfl_xor(pB, 4, 8);
    if (gl == 0) {
      if (iA < deg) {
        float ev = __expf(__expf(pA) * 4.0f);
        EV[beg + iA] = ev;
        unsafeAtomicAdd(&DEN[sA], ev);
      }
      if (iB < deg) {
        float ev = __expf(__expf(pB) * 4.0f);
        EV[beg + iB] = ev;
        unsafeAtomicAdd(&DEN[sB], ev);
      }
    }
  }
}

// ---- pass2: 8 lanes/edge, acc += (ev/den[s]) * xlb[s] ----
__global__ __launch_bounds__(256) void gat_dst_k(const uint4* __restrict__ XLB,
                                                 const float* __restrict__ EV,
                                                 const float* __restrict__ DEN,
                                                 const int* __restrict__ off_d,
                                                 const int* __restrict__ dl_src,
                                                 float* __restrict__ AGG, int n) {
  int wv = threadIdx.x >> 6, lane = threadIdx.x & 63;
  int node = blockIdx.x * 4 + wv;
  if (node >= n) return;
  int g = lane >> 3, gl = lane & 7;
  int beg = off_d[node];
  int deg = off_d[node + 1] - beg;
  float4 a0 = {0.f, 0.f, 0.f, 0.f}, a1 = {0.f, 0.f, 0.f, 0.f};
  for (int i0 = 0; i0 < deg; i0 += 16) {
    int iA = i0 + g, iB = iA + 8;
    int sA = dl_src[beg + ((iA < deg) ? iA : 0)];
    int sB = dl_src[beg + ((iB < deg) ? iB : 0)];
    uint4 hA = XLB[(size_t)sA * 8 + gl];
    uint4 hB = XLB[(size_t)sB * 8 + gl];
    float wA = 0.f, wB = 0.f;
    if (gl == 0) {
      if (iA < deg) wA = EV[beg + iA] / DEN[sA];
      if (iB < deg) wB = EV[beg + iB] / DEN[sB];
    }
    wA = __shfl(wA, 0, 8);
    wB = __shfl(wB, 0, 8);
    fma8(hA, wA, a0, a1);
    fma8(hB, wB, a0, a1);
  }
#pragma unroll
  for (int o = 8; o < 64; o <<= 1) {
    a0.x += __shfl_xor(a0.x, o); a0.y += __shfl_xor(a0.y, o);
    a0.z += __shfl_xor(a0.z, o); a0.w += __shfl_xor(a0.w, o);
    a1.x += __shfl_xor(a1.x, o); a1.y += __shfl_xor(a1.y, o);
    a1.z += __shfl_xor(a1.z, o); a1.w += __shfl_xor(a1.w, o);
  }
  if (g == 0) {
    *(float4*)&AGG[(size_t)node * 64 + gl * 8]     = a0;
    *(float4*)&AGG[(size_t)node * 64 + gl * 8 + 4] = a1;
  }
}

extern "C" void kernel_launch(void* const* d_in, const int* in_sizes, int n_in,
                              void* d_out, int out_size, void* d_ws, size_t ws_size,
                              hipStream_t stream) {
  const int N = in_sizes[0] / IN_C;
  const int E = in_sizes[1] / 2;
  const int* ei  = (const int*)d_in[1];
  const int* src = ei;
  const int* dst = ei + E;

  char* wsb = (char*)d_ws;
  size_t o = 0;
  auto alloc = [&](size_t elems) { void* p = wsb + o; o += ((elems + 3) & ~3ull) * 4; return p; };
  int*   FLAG   = (int*)alloc(16);
  float* WF     = (float*)alloc(60000);
  int*   CNT_D  = (int*)alloc(N);
  int*   OFF_D  = (int*)alloc(N + 1);
  int*   CUR_D  = (int*)alloc(N);
  int*   PART   = (int*)alloc(256);
  int*   DL_SRC = (int*)alloc(E);
  float* EV     = (float*)alloc(E);
  float* DEN    = (float*)alloc(N);
  uint4* XLB    = (uint4*)alloc((size_t)N * 32);
  uint4* XLN    = (uint4*)alloc((size_t)N * 32);
  float* bufA   = (float*)alloc((size_t)N * 128);
  float* bufB   = (float*)alloc((size_t)N * 128);

  float* XF  = bufA;
  float* XRN = bufA + (size_t)N * 64;
  float* H0  = bufB;
  float* B1  = bufB;
  float* B2  = bufB + (size_t)N * 64;

  dim3 blk(256);
  auto nblk = [](long total, int per) { return dim3((unsigned)((total + per - 1) / per)); };

  // ---- dtype detect + convert ----
  detect_k<<<1, blk, 0, stream>>>((const unsigned short*)d_in[0], FLAG);
  cvt_k<<<nblk((long)N * 128, 256), blk, 0, stream>>>(d_in[0], XF, N * 128, FLAG);
  WArgs wa;
  int wtot = 0;
  float* wp[16];
  for (int i = 2; i < 16; i++) {
    wa.p[i - 2] = d_in[i];
    wa.off[i - 2] = wtot;
    wp[i] = WF + wtot;
    wtot += in_sizes[i];
  }
  wa.off[14] = wtot;
  cvtw_k<<<nblk(wtot, 256), blk, 0, stream>>>(wa, WF, FLAG, wtot);
  const float *W_in = wp[2], *b_in = wp[3], *Wl1 = wp[4], *Wr1 = wp[5],
              *bias1 = wp[6], *Wc1 = wp[7], *Wl2 = wp[8], *Wr2 = wp[9],
              *bias2 = wp[10], *Wc2 = wp[11], *W3 = wp[12], *b3 = wp[13],
              *W4 = wp[14], *b4 = wp[15];

  // ---- CSR build (dst side only) ----
  hipMemsetAsync(CNT_D, 0, sizeof(int) * (size_t)N, stream);
  count_k<<<nblk(E, 256), blk, 0, stream>>>(dst, CNT_D, E);
  {
    int nb = (N + 2047) / 2048;
    scan_local_k<<<dim3(nb), blk, 0, stream>>>(CNT_D, OFF_D, PART, N);
    scan_add_k<<<dim3(nb), blk, 0, stream>>>(OFF_D, CUR_D, PART, nb, N);
  }
  fill_k<<<dim3(2048), blk, 0, stream>>>(src, dst, CUR_D, DL_SRC, E, N);

  // h0 = leaky(x @ W_in + b_in)  [K=128,C=128,R=8 -> RPB=64]
  lin_k<128, 128, 8, 1, false, true, 0>
      <<<nblk(N, 64), blk, 0, stream>>>(XF, W_in, nullptr, b_in, H0, nullptr, N);

  // ---- GAT layer 1 ----
  lin_k<128, 64, 4, 0, false, false, 4>   // RPB=64
      <<<nblk(N, 64), blk, 0, stream>>>(H0, Wl1, nullptr, nullptr, (float*)XLB, (float*)XLN, N);
  lin_k<128, 64, 4, 0, false, false, 1>
      <<<nblk(N, 64), blk, 0, stream>>>(H0, Wr1, nullptr, nullptr, XRN, nullptr, N);
  hipMemsetAsync(DEN, 0, sizeof(float) * (size_t)N, stream);
  gat_pre_k<<<nblk(N, 4), blk, 0, stream>>>(XLN, XRN, OFF_D, DL_SRC, EV, DEN, N);
  gat_dst_k<<<nblk(N, 4), blk, 0, stream>>>(XLB, EV, DEN, OFF_D, DL_SRC, B1, N);
  lin_k<64, 64, 8, 1, true, false, 0>     // RPB=128
      <<<nblk(N, 128), blk, 0, stream>>>(B1, Wc1, bias1, nullptr, B1, nullptr, N);

  // ---- GAT layer 2 ----
  lin_k<64, 64, 8, 0, false, false, 4>
      <<<nblk(N, 128), blk, 0, stream>>>(B1, Wl2, nullptr, nullptr, (float*)XLB, (float*)XLN, N);
  lin_k<64, 64, 8, 0, false, false, 1>
      <<<nblk(N, 128), blk, 0, stream>>>(B1, Wr2, nullptr, nullptr, XRN, nullptr, N);
  hipMemsetAsync(DEN, 0, sizeof(float) * (size_t)N, stream);
  gat_pre_k<<<nblk(N, 4), blk, 0, stream>>>(XLN, XRN, OFF_D, DL_SRC, EV, DEN, N);
  gat_dst_k<<<nblk(N, 4), blk, 0, stream>>>(XLB, EV, DEN, OFF_D, DL_SRC, B2, N);
  lin_k<64, 64, 8, 1, true, false, 0>
      <<<nblk(N, 128), blk, 0, stream>>>(B2, Wc2, bias2, nullptr, B2, nullptr, N);

  // ---- head ----
  lin_k<64, 64, 8, 2, false, true, 0>
      <<<nblk(N, 128), blk, 0, stream>>>(B2, W3, nullptr, b3, B1, nullptr, N);
  lin_k<64, 32, 4, 0, false, true, 0>     // CG=8, RG=32, RPB=128
      <<<nblk(N, 128), blk, 0, stream>>>(B1, W4, nullptr, b4, bufA, nullptr, N);
  out_k<<<nblk((long)N * 32, 256), blk, 0, stream>>>(bufA, d_out, N * 32, FLAG);
}

// Round 10
// 749.639 us; speedup vs baseline: 2.0844x; 1.3178x over previous
//
#include <hip/hip_runtime.h>
#include <hip/hip_bf16.h>

typedef __hip_bfloat16 bf16;

#define IN_C 128

__device__ inline unsigned short f2bf(float f) {
  bf16 b = __float2bfloat16(f);
  return __builtin_bit_cast(unsigned short, b);
}

// ---- dtype detection: flag=1 if buffer is bf16, 0 if float32 ----
__global__ __launch_bounds__(256) void detect_k(const unsigned short* __restrict__ xb,
                                                int* __restrict__ flag) {
  __shared__ int s_sane;
  if (threadIdx.x == 0) s_sane = 0;
  __syncthreads();
  int sane = 0;
  for (int i = threadIdx.x; i < 4096; i += 256) {
    unsigned short h = xb[2 * i];
    int e = (h >> 7) & 0xFF;
    if (e >= 100 && e <= 150) sane++;
  }
  atomicAdd(&s_sane, sane);
  __syncthreads();
  if (threadIdx.x == 0) *flag = (s_sane > 3072) ? 1 : 0;
}

__global__ __launch_bounds__(256) void cvt_k(const void* __restrict__ in,
                                             float* __restrict__ out, int n,
                                             const int* __restrict__ flag) {
  int i = blockIdx.x * 256 + threadIdx.x;
  if (i >= n) return;
  if (*flag) out[i] = __bfloat162float(((const bf16*)in)[i]);
  else       out[i] = ((const float*)in)[i];
}

struct WArgs { const void* p[14]; int off[15]; };
__global__ __launch_bounds__(256) void cvtw_k(WArgs a, float* __restrict__ out,
                                              const int* __restrict__ flag, int total) {
  int i = blockIdx.x * 256 + threadIdx.x;
  if (i >= total) return;
  int s = 0;
#pragma unroll
  for (int j = 1; j < 14; j++) if (i >= a.off[j]) s = j;
  int loc = i - a.off[s];
  if (*flag) out[i] = __bfloat162float(((const bf16*)a.p[s])[loc]);
  else       out[i] = ((const float*)a.p[s])[loc];
}

__global__ __launch_bounds__(256) void out_k(const float* __restrict__ src,
                                             void* __restrict__ out, int n,
                                             const int* __restrict__ flag) {
  int i = blockIdx.x * 256 + threadIdx.x;
  if (i >= n) return;
  float v = src[i];
  if (*flag) ((bf16*)out)[i] = __float2bfloat16(v);
  else       ((float*)out)[i] = v;
}

// ---- register-tiled linear, LDS-only hot loop ----
// out[n,C] = act((x[n,K]+preb) @ W[K,C] + postb)
// Thread (cg,g): 4 cols (c0=cg*4) x R rows (row = r*RG + g, interleaved).
// xs rows padded to K+4 floats -> g-stride 4 banks (conflict-free);
// W staged into ws in KC-row chunks -> no global loads in the K-loop.
// ACT: 0 none, 1 leaky(0.01), 2 relu.
// NRM: 0 none; 1 out=f32 normalized rows; 4 out=bf16 raw, out2=bf16 normalized.
template <int K, int C, int R, int ACT, bool PREB, bool POSTB, int NRM>
__global__ __launch_bounds__(256, 2) void lin_k(const float* __restrict__ x,
                                                const float* __restrict__ W,
                                                const float* __restrict__ preb,
                                                const float* __restrict__ postb,
                                                float* __restrict__ out,
                                                float* __restrict__ out2, int n) {
  constexpr int CG  = C / 4;
  constexpr int RG  = 256 / CG;
  constexpr int RPB = RG * R;
  constexpr int KP  = K + 4;
  constexpr int KC  = (K < 4096 / C) ? K : (4096 / C);  // ws <= 16KB
  __shared__ float xs[RPB * KP];
  __shared__ float ws[KC * C];
  const int tid = threadIdx.x;
  const int row0 = blockIdx.x * RPB;

  // stage x (+preb) into LDS, float4-vectorized, padded rows
  for (int i = tid; i < RPB * K / 4; i += 256) {
    int r4 = i / (K / 4);
    int kk = (i - r4 * (K / 4)) * 4;
    int row = row0 + r4;
    float4 v = make_float4(0.f, 0.f, 0.f, 0.f);
    if (row < n) v = *(const float4*)&x[(size_t)row * K + kk];
    if (PREB) {
      v.x += preb[kk]; v.y += preb[kk + 1]; v.z += preb[kk + 2]; v.w += preb[kk + 3];
    }
    *(float4*)&xs[r4 * KP + kk] = v;
  }

  const int cg = tid % CG;
  const int g  = tid / CG;
  const int c0 = cg * 4;

  float4 acc[R];
#pragma unroll
  for (int r = 0; r < R; r++) acc[r] = make_float4(0.f, 0.f, 0.f, 0.f);

  for (int kc0 = 0; kc0 < K; kc0 += KC) {
    // stage W chunk [KC x C]
    for (int i = tid; i < KC * C / 4; i += 256) {
      *(float4*)&ws[i * 4] = *(const float4*)&W[(size_t)kc0 * C + i * 4];
    }
    __syncthreads();  // xs (first iter) + ws ready
#pragma unroll 4
    for (int k = 0; k < KC; k += 4) {
      const float* wb = &ws[k * C + c0];
      float4 w0 = *(const float4*)(wb);
      float4 w1 = *(const float4*)(wb + C);
      float4 w2 = *(const float4*)(wb + 2 * C);
      float4 w3 = *(const float4*)(wb + 3 * C);
#pragma unroll
      for (int r = 0; r < R; r++) {
        float4 xv = *(const float4*)&xs[(r * RG + g) * KP + kc0 + k];
        float4 a = acc[r];
        a.x = fmaf(xv.x, w0.x, a.x); a.y = fmaf(xv.x, w0.y, a.y);
        a.z = fmaf(xv.x, w0.z, a.z); a.w = fmaf(xv.x, w0.w, a.w);
        a.x = fmaf(xv.y, w1.x, a.x); a.y = fmaf(xv.y, w1.y, a.y);
        a.z = fmaf(xv.y, w1.z, a.z); a.w = fmaf(xv.y, w1.w, a.w);
        a.x = fmaf(xv.z, w2.x, a.x); a.y = fmaf(xv.z, w2.y, a.y);
        a.z = fmaf(xv.z, w2.z, a.z); a.w = fmaf(xv.z, w2.w, a.w);
        a.x = fmaf(xv.w, w3.x, a.x); a.y = fmaf(xv.w, w3.y, a.y);
        a.z = fmaf(xv.w, w3.z, a.z); a.w = fmaf(xv.w, w3.w, a.w);
        acc[r] = a;
      }
    }
    __syncthreads();  // compute done before ws restage
  }

  float4 pb = make_float4(0.f, 0.f, 0.f, 0.f);
  if (POSTB) pb = *(const float4*)&postb[c0];
#pragma unroll
  for (int r = 0; r < R; r++) {
    int row = row0 + r * RG + g;
    float4 v = acc[r];
    v.x += pb.x; v.y += pb.y; v.z += pb.z; v.w += pb.w;
    if (ACT == 1) {
      v.x = (v.x >= 0.f) ? v.x : 0.01f * v.x; v.y = (v.y >= 0.f) ? v.y : 0.01f * v.y;
      v.z = (v.z >= 0.f) ? v.z : 0.01f * v.z; v.w = (v.w >= 0.f) ? v.w : 0.01f * v.w;
    }
    if (ACT == 2) {
      v.x = fmaxf(v.x, 0.f); v.y = fmaxf(v.y, 0.f);
      v.z = fmaxf(v.z, 0.f); v.w = fmaxf(v.w, 0.f);
    }
    if (NRM == 0) {
      if (row < n) *(float4*)&out[(size_t)row * C + c0] = v;
    } else {
      float ss = v.x * v.x + v.y * v.y + v.z * v.z + v.w * v.w;
#pragma unroll
      for (int o = 1; o < CG; o <<= 1) ss += __shfl_xor(ss, o, CG);
      float inv = 1.0f / fmaxf(sqrtf(ss), 1e-12f);
      if (row < n) {
        if (NRM == 1) {
          float4 vn = make_float4(v.x * inv, v.y * inv, v.z * inv, v.w * inv);
          *(float4*)&out[(size_t)row * C + c0] = vn;
        } else {  // NRM == 4
          ushort4 hr = make_ushort4(f2bf(v.x), f2bf(v.y), f2bf(v.z), f2bf(v.w));
          ushort4 hn = make_ushort4(f2bf(v.x * inv), f2bf(v.y * inv),
                                    f2bf(v.z * inv), f2bf(v.w * inv));
          *(ushort4*)((bf16*)out  + (size_t)row * C + c0) = hr;
          *(ushort4*)((bf16*)out2 + (size_t)row * C + c0) = hn;
        }
      }
    }
  }
}

// ---- CSR build (dst side only) ----
__global__ __launch_bounds__(256) void count_k(const int* __restrict__ dst,
                                               int* __restrict__ cnt_d, int E) {
  int e = blockIdx.x * 256 + threadIdx.x;
  if (e >= E) return;
  atomicAdd(&cnt_d[dst[e]], 1);
}

__global__ __launch_bounds__(256) void scan_local_k(const int* __restrict__ cnt,
                                                    int* __restrict__ off,
                                                    int* __restrict__ part, int n) {
  __shared__ int sd[256];
  int t = threadIdx.x;
  int base = blockIdx.x * 2048 + t * 8;
  int v[8], s = 0;
#pragma unroll
  for (int j = 0; j < 8; j++) {
    int idx = base + j;
    v[j] = (idx < n) ? cnt[idx] : 0;
    s += v[j];
  }
  sd[t] = s;
  __syncthreads();
  for (int o = 1; o < 256; o <<= 1) {
    int x = (t >= o) ? sd[t - o] : 0;
    __syncthreads();
    sd[t] += x;
    __syncthreads();
  }
  int excl = sd[t] - s;
  if (t == 255) part[blockIdx.x] = sd[255];
  int run = excl;
#pragma unroll
  for (int j = 0; j < 8; j++) {
    int idx = base + j;
    if (idx < n) off[idx] = run;
    run += v[j];
  }
}

__global__ __launch_bounds__(256) void scan_add_k(int* __restrict__ off,
                                                  int* __restrict__ cur,
                                                  const int* __restrict__ part,
                                                  int nb, int n) {
  __shared__ int s_pref;
  if (threadIdx.x == 0) {
    int s = 0;
    for (int i = 0; i < (int)blockIdx.x; i++) s += part[i];
    s_pref = s;
    if (blockIdx.x == 0) {
      int tot = 0;
      for (int i = 0; i < nb; i++) tot += part[i];
      off[n] = tot;
    }
  }
  __syncthreads();
  int pref = s_pref;
  int base = blockIdx.x * 2048 + threadIdx.x * 8;
#pragma unroll
  for (int j = 0; j < 8; j++) {
    int idx = base + j;
    if (idx < n) { int val = off[idx] + pref; off[idx] = val; cur[idx] = val; }
  }
}

// fill: XCD-partitioned (group k=blockIdx&7 handles dst slice k)
__global__ __launch_bounds__(256) void fill_k(const int* __restrict__ src,
                                              const int* __restrict__ dst,
                                              int* __restrict__ cur_d,
                                              int* __restrict__ dl_src, int E, int N) {
  int part = blockIdx.x & 7;
  int lo = (int)(((long)part * N) >> 3);
  int hi = (int)((((long)part + 1) * N) >> 3);
  int tid = (blockIdx.x >> 3) * 256 + threadIdx.x;
  int stride = (gridDim.x >> 3) * 256;
  for (int e = tid; e < E; e += stride) {
    int d = dst[e];
    if (d < lo || d >= hi) continue;
    int pd = atomicAdd(&cur_d[d], 1);
    dl_src[pd] = src[e];
  }
}

__device__ inline float dot8(uint4 h, float4 r0, float4 r1) {
  float p;
  p  = __uint_as_float(h.x << 16) * r0.x + __uint_as_float(h.x & 0xffff0000u) * r0.y;
  p += __uint_as_float(h.y << 16) * r0.z + __uint_as_float(h.y & 0xffff0000u) * r0.w;
  p += __uint_as_float(h.z << 16) * r1.x + __uint_as_float(h.z & 0xffff0000u) * r1.y;
  p += __uint_as_float(h.w << 16) * r1.z + __uint_as_float(h.w & 0xffff0000u) * r1.w;
  return p;
}

__device__ inline void fma8(uint4 h, float w, float4& a0, float4& a1) {
  a0.x += w * __uint_as_float(h.x << 16); a0.y += w * __uint_as_float(h.x & 0xffff0000u);
  a0.z += w * __uint_as_float(h.y << 16); a0.w += w * __uint_as_float(h.y & 0xffff0000u);
  a1.x += w * __uint_as_float(h.z << 16); a1.y += w * __uint_as_float(h.z & 0xffff0000u);
  a1.z += w * __uint_as_float(h.w << 16); a1.w += w * __uint_as_float(h.w & 0xffff0000u);
}

// ---- pass1: 8 lanes/edge, 16 edges in flight/wave ----
__global__ __launch_bounds__(256) void gat_pre_k(const uint4* __restrict__ XLN,
                                                 const float* __restrict__ XRN,
                                                 const int* __restrict__ off_d,
                                                 const int* __restrict__ dl_src,
                                                 float* __restrict__ EV,
                                                 float* __restrict__ DEN, int n) {
  int wv = threadIdx.x >> 6, lane = threadIdx.x & 63;
  int node = blockIdx.x * 4 + wv;
  if (node >= n) return;
  int g = lane >> 3, gl = lane & 7;
  int beg = off_d[node];
  int deg = off_d[node + 1] - beg;
  if (deg <= 0) return;
  const float4* xrp = (const float4*)&XRN[(size_t)node * 64 + gl * 8];
  float4 xr0 = xrp[0], xr1 = xrp[1];
  for (int i0 = 0; i0 < deg; i0 += 16) {
    int iA = i0 + g, iB = iA + 8;
    int sA = dl_src[beg + ((iA < deg) ? iA : 0)];
    int sB = dl_src[beg + ((iB < deg) ? iB : 0)];
    uint4 hA = XLN[(size_t)sA * 8 + gl];
    uint4 hB = XLN[(size_t)sB * 8 + gl];
    float pA = dot8(hA, xr0, xr1);
    float pB = dot8(hB, xr0, xr1);
    pA += __shfl_xor(pA, 1, 8); pA += __shfl_xor(pA, 2, 8); pA += __shfl_xor(pA, 4, 8);
    pB += __shfl_xor(pB, 1, 8); pB += __shfl_xor(pB, 2, 8); pB += __shfl_xor(pB, 4, 8);
    if (gl == 0) {
      if (iA < deg) {
        float ev = __expf(__expf(pA) * 4.0f);
        EV[beg + iA] = ev;
        unsafeAtomicAdd(&DEN[sA], ev);
      }
      if (iB < deg) {
        float ev = __expf(__expf(pB) * 4.0f);
        EV[beg + iB] = ev;
        unsafeAtomicAdd(&DEN[sB], ev);
      }
    }
  }
}

// ---- pass2: 8 lanes/edge, acc += (ev/den[s]) * xlb[s] ----
__global__ __launch_bounds__(256) void gat_dst_k(const uint4* __restrict__ XLB,
                                                 const float* __restrict__ EV,
                                                 const float* __restrict__ DEN,
                                                 const int* __restrict__ off_d,
                                                 const int* __restrict__ dl_src,
                                                 float* __restrict__ AGG, int n) {
  int wv = threadIdx.x >> 6, lane = threadIdx.x & 63;
  int node = blockIdx.x * 4 + wv;
  if (node >= n) return;
  int g = lane >> 3, gl = lane & 7;
  int beg = off_d[node];
  int deg = off_d[node + 1] - beg;
  float4 a0 = {0.f, 0.f, 0.f, 0.f}, a1 = {0.f, 0.f, 0.f, 0.f};
  for (int i0 = 0; i0 < deg; i0 += 16) {
    int iA = i0 + g, iB = iA + 8;
    int sA = dl_src[beg + ((iA < deg) ? iA : 0)];
    int sB = dl_src[beg + ((iB < deg) ? iB : 0)];
    uint4 hA = XLB[(size_t)sA * 8 + gl];
    uint4 hB = XLB[(size_t)sB * 8 + gl];
    float wA = 0.f, wB = 0.f;
    if (gl == 0) {
      if (iA < deg) wA = EV[beg + iA] / DEN[sA];
      if (iB < deg) wB = EV[beg + iB] / DEN[sB];
    }
    wA = __shfl(wA, 0, 8);
    wB = __shfl(wB, 0, 8);
    fma8(hA, wA, a0, a1);
    fma8(hB, wB, a0, a1);
  }
#pragma unroll
  for (int o = 8; o < 64; o <<= 1) {
    a0.x += __shfl_xor(a0.x, o); a0.y += __shfl_xor(a0.y, o);
    a0.z += __shfl_xor(a0.z, o); a0.w += __shfl_xor(a0.w, o);
    a1.x += __shfl_xor(a1.x, o); a1.y += __shfl_xor(a1.y, o);
    a1.z += __shfl_xor(a1.z, o); a1.w += __shfl_xor(a1.w, o);
  }
  if (g == 0) {
    *(float4*)&AGG[(size_t)node * 64 + gl * 8]     = a0;
    *(float4*)&AGG[(size_t)node * 64 + gl * 8 + 4] = a1;
  }
}

extern "C" void kernel_launch(void* const* d_in, const int* in_sizes, int n_in,
                              void* d_out, int out_size, void* d_ws, size_t ws_size,
                              hipStream_t stream) {
  const int N = in_sizes[0] / IN_C;
  const int E = in_sizes[1] / 2;
  const int* ei  = (const int*)d_in[1];
  const int* src = ei;
  const int* dst = ei + E;

  char* wsb = (char*)d_ws;
  size_t o = 0;
  auto alloc = [&](size_t elems) { void* p = wsb + o; o += ((elems + 3) & ~3ull) * 4; return p; };
  int*   FLAG   = (int*)alloc(16);
  float* WF     = (float*)alloc(60000);
  int*   CNT_D  = (int*)alloc(N);
  int*   OFF_D  = (int*)alloc(N + 1);
  int*   CUR_D  = (int*)alloc(N);
  int*   PART   = (int*)alloc(256);
  int*   DL_SRC = (int*)alloc(E);
  float* EV     = (float*)alloc(E);
  float* DEN    = (float*)alloc(N);
  uint4* XLB    = (uint4*)alloc((size_t)N * 32);
  uint4* XLN    = (uint4*)alloc((size_t)N * 32);
  float* bufA   = (float*)alloc((size_t)N * 128);
  float* bufB   = (float*)alloc((size_t)N * 128);

  float* XF  = bufA;
  float* XRN = bufA + (size_t)N * 64;
  float* H0  = bufB;
  float* B1  = bufB;
  float* B2  = bufB + (size_t)N * 64;

  dim3 blk(256);
  auto nblk = [](long total, int per) { return dim3((unsigned)((total + per - 1) / per)); };

  // ---- dtype detect + convert ----
  detect_k<<<1, blk, 0, stream>>>((const unsigned short*)d_in[0], FLAG);
  cvt_k<<<nblk((long)N * 128, 256), blk, 0, stream>>>(d_in[0], XF, N * 128, FLAG);
  WArgs wa;
  int wtot = 0;
  float* wp[16];
  for (int i = 2; i < 16; i++) {
    wa.p[i - 2] = d_in[i];
    wa.off[i - 2] = wtot;
    wp[i] = WF + wtot;
    wtot += in_sizes[i];
  }
  wa.off[14] = wtot;
  cvtw_k<<<nblk(wtot, 256), blk, 0, stream>>>(wa, WF, FLAG, wtot);
  const float *W_in = wp[2], *b_in = wp[3], *Wl1 = wp[4], *Wr1 = wp[5],
              *bias1 = wp[6], *Wc1 = wp[7], *Wl2 = wp[8], *Wr2 = wp[9],
              *bias2 = wp[10], *Wc2 = wp[11], *W3 = wp[12], *b3 = wp[13],
              *W4 = wp[14], *b4 = wp[15];

  // ---- CSR build (dst side only) ----
  hipMemsetAsync(CNT_D, 0, sizeof(int) * (size_t)N, stream);
  count_k<<<nblk(E, 256), blk, 0, stream>>>(dst, CNT_D, E);
  {
    int nb = (N + 2047) / 2048;
    scan_local_k<<<dim3(nb), blk, 0, stream>>>(CNT_D, OFF_D, PART, N);
    scan_add_k<<<dim3(nb), blk, 0, stream>>>(OFF_D, CUR_D, PART, nb, N);
  }
  fill_k<<<dim3(2048), blk, 0, stream>>>(src, dst, CUR_D, DL_SRC, E, N);

  // h0 = leaky(x @ W_in + b_in)  [RPB=64]
  lin_k<128, 128, 8, 1, false, true, 0>
      <<<nblk(N, 64), blk, 0, stream>>>(XF, W_in, nullptr, b_in, H0, nullptr, N);

  // ---- GAT layer 1 ----
  lin_k<128, 64, 4, 0, false, false, 4>   // RPB=64
      <<<nblk(N, 64), blk, 0, stream>>>(H0, Wl1, nullptr, nullptr, (float*)XLB, (float*)XLN, N);
  lin_k<128, 64, 4, 0, false, false, 1>
      <<<nblk(N, 64), blk, 0, stream>>>(H0, Wr1, nullptr, nullptr, XRN, nullptr, N);
  hipMemsetAsync(DEN, 0, sizeof(float) * (size_t)N, stream);
  gat_pre_k<<<nblk(N, 4), blk, 0, stream>>>(XLN, XRN, OFF_D, DL_SRC, EV, DEN, N);
  gat_dst_k<<<nblk(N, 4), blk, 0, stream>>>(XLB, EV, DEN, OFF_D, DL_SRC, B1, N);
  lin_k<64, 64, 8, 1, true, false, 0>     // RPB=128
      <<<nblk(N, 128), blk, 0, stream>>>(B1, Wc1, bias1, nullptr, B1, nullptr, N);

  // ---- GAT layer 2 ----
  lin_k<64, 64, 8, 0, false, false, 4>
      <<<nblk(N, 128), blk, 0, stream>>>(B1, Wl2, nullptr, nullptr, (float*)XLB, (float*)XLN, N);
  lin_k<64, 64, 8, 0, false, false, 1>
      <<<nblk(N, 128), blk, 0, stream>>>(B1, Wr2, nullptr, nullptr, XRN, nullptr, N);
  hipMemsetAsync(DEN, 0, sizeof(float) * (size_t)N, stream);
  gat_pre_k<<<nblk(N, 4), blk, 0, stream>>>(XLN, XRN, OFF_D, DL_SRC, EV, DEN, N);
  gat_dst_k<<<nblk(N, 4), blk, 0, stream>>>(XLB, EV, DEN, OFF_D, DL_SRC, B2, N);
  lin_k<64, 64, 8, 1, true, false, 0>
      <<<nblk(N, 128), blk, 0, stream>>>(B2, Wc2, bias2, nullptr, B2, nullptr, N);

  // ---- head ----
  lin_k<64, 64, 8, 2, false, true, 0>
      <<<nblk(N, 128), blk, 0, stream>>>(B2, W3, nullptr, b3, B1, nullptr, N);
  lin_k<64, 32, 4, 0, false, true, 0>     // CG=8, RG=32, RPB=128
      <<<nblk(N, 128), blk, 0, stream>>>(B1, W4, nullptr, b4, bufA, nullptr, N);
  out_k<<<nblk((long)N * 32, 256), blk, 0, stream>>>(bufA, d_out, N * 32, FLAG);
}